// Round 6
// baseline (1270.261 us; speedup 1.0000x reference)
//
#include <hip/hip_runtime.h>

// InteractionNetwork — fused MFMA, transposed-product formulation + dst-sorted
// edge processing. Device counting-sort (hist/scan/scatter) yields perm/dstS;
// edge MLP runs in sorted order so the segment-sum becomes per-run (avg 16
// edges) LDS reductions with ONE row-atomic per run instead of per edge.
// Weight frags persistent in regs (deduped), bias/LN params in LDS, epilogue
// writes LN'd rows to fp32 LDS then a coalesced writer phase.

#define NNODES 50000
#define NEDGES 800000
#define NBLK 512

typedef __bf16 bf16x8 __attribute__((ext_vector_type(8)));
typedef float f32x4 __attribute__((ext_vector_type(4)));
#define MFMA(a, b, c) __builtin_amdgcn_mfma_f32_16x16x32_bf16(a, b, c, 0, 0, 0)

// LDS map (bytes)
#define OFF_A 0       // [64 rows][192 bf16] stride 384, XOR-swizzled; [0,256) reused as H1; [256,384) = residual seg
#define OFF_H0 24576  // [64 rows][128 bf16] stride 256, XOR-swizzled; reused as O [64][64] f32 after L1
#define OFF_O OFF_H0
#define OFF_SA 40960  // DMA strip: 16 chunks x (1024B data + 16B pad) = 16640
#define OFF_P 57600   // [64 rows][4 float2] partial (s,ss) = 2048
#define OFF_IX 59648  // [64] int sorted dst indices = 256
#define OFF_PAR 59904 // param block: b0[128] b1[128] b2[64] gam[64] bet[64] = 448 f32
#define SMEM 61696

__device__ __forceinline__ unsigned short f2bf(float f) {
  unsigned u = __builtin_bit_cast(unsigned, f);
  u = (u + 0x7fffu + ((u >> 16) & 1u)) >> 16;
  return (unsigned short)u;
}
__device__ __forceinline__ float bf2f(unsigned short h) {
  return __builtin_bit_cast(float, (unsigned)h << 16);
}
__device__ __forceinline__ unsigned long long pk4(f32x4 v) {
  union { unsigned short h[4]; unsigned long long u; } p;
  p.h[0] = f2bf(v[0]); p.h[1] = f2bf(v[1]); p.h[2] = f2bf(v[2]); p.h[3] = f2bf(v[3]);
  return p.u;
}
__device__ __forceinline__ void cvt8s(float4 f0, float4 f1, char* d) {
  union { unsigned short us[8]; int4 v; } u;
  u.us[0] = f2bf(f0.x); u.us[1] = f2bf(f0.y); u.us[2] = f2bf(f0.z); u.us[3] = f2bf(f0.w);
  u.us[4] = f2bf(f1.x); u.us[5] = f2bf(f1.y); u.us[6] = f2bf(f1.z); u.us[7] = f2bf(f1.w);
  *(int4*)d = u.v;
}

// EDGE: rows are sorted edges; A = [x[dst] | x[src] | attr(DMA via perm)],
//       resid = attr, segmented run-atomics into agg, out scattered via perm.
// NODE: A = [aggm | aggw | x(DMA)], resid = x (seg2), no atomics.
template <bool EDGE>
__global__ __launch_bounds__(512, 4) void mlp_block(
    const float* __restrict__ g1, const float* __restrict__ g2,
    const float* __restrict__ g3, const int* __restrict__ srcI,
    const int* __restrict__ perm, const int* __restrict__ dstS,
    const unsigned short* __restrict__ Wt,
    const float* __restrict__ b0, const float* __restrict__ b1,
    const float* __restrict__ b2, const float* __restrict__ gam,
    const float* __restrict__ bet, float* __restrict__ outp,
    float* __restrict__ agg, int M) {
  __shared__ __align__(16) char sm[SMEM];
  const int tid = threadIdx.x, lane = tid & 63, wave = tid >> 6;
  const int lrow = lane & 15, cg = lane >> 4;
  const unsigned short* Wt0 = Wt;
  const unsigned short* Wt1 = Wt + 24576;
  const unsigned short* Wt2 = Wt + 40960;
  const int ntiles = (M + 63) >> 6;

  const int cg2 = wave & 3, rg = wave >> 2;

  // ---- stage bias/LN params into LDS ----
  for (int i = tid; i < 448; i += 512) {
    float v;
    if (i < 128) v = b0[i];
    else if (i < 256) v = b1[i - 128];
    else if (i < 320) v = b2[i - 256];
    else if (i < 384) v = gam[i - 320];
    else v = bet[i - 384];
    ((float*)(sm + OFF_PAR))[i] = v;
  }
  const float* PAR = (const float*)(sm + OFF_PAR);

  // ---- persistent weight fragments, deduped ----
  bf16x8 w0f[6], w1f[4], w2f[4];
#pragma unroll
  for (int kk = 0; kk < 6; ++kk)
    w0f[kk] = *(const bf16x8*)(Wt0 + (wave * 16 + lrow) * 192 + kk * 32 + cg * 8);
#pragma unroll
  for (int kk = 0; kk < 4; ++kk)
    w1f[kk] = *(const bf16x8*)(Wt1 + (wave * 16 + lrow) * 128 + kk * 32 + cg * 8);
#pragma unroll
  for (int kk = 0; kk < 4; ++kk)
    w2f[kk] = *(const bf16x8*)(Wt2 + (cg2 * 16 + lrow) * 128 + kk * 32 + cg * 8);

  // staging map: row = (tid>>5)*4 + ((tid&31)>>3), float-octet oct = tid&7
  const int srow = (tid >> 5) * 4 + ((tid & 31) >> 3), oct = tid & 7;

  int t = blockIdx.x;
  if (t >= ntiles) return;

  // ---- prologue: prefetch tile t ----
  float4 ga0, ga1, gb0, gb1;
  int dcur = 0;
  {
    int row = t * 64 + srow;
    int r1, r2;
    if (EDGE) {
      int e = perm[row];
      dcur = dstS[row];
      r1 = dcur; r2 = srcI[e];
    } else { int rr = min(row, M - 1); r1 = rr; r2 = rr; }
    const float* p1 = g1 + (size_t)r1 * 64 + oct * 8;
    const float* p2 = g2 + (size_t)r2 * 64 + oct * 8;
    ga0 = *(const float4*)p1; ga1 = *(const float4*)(p1 + 4);
    gb0 = *(const float4*)p2; gb1 = *(const float4*)(p2 + 4);
#pragma unroll
    for (int i = 0; i < 2; ++i) {
      int chunk = wave * 2 + i;
      const float* gsrc;
      if (EDGE) {
        int er = perm[t * 64 + chunk * 4 + (lane >> 4)];
        gsrc = g3 + (size_t)er * 64 + (lane & 15) * 4;
      } else { int gr = min(t * 64 + chunk * 4 + (lane >> 4), M - 1); gsrc = g3 + (size_t)gr * 64 + (lane & 15) * 4; }
      __builtin_amdgcn_global_load_lds((const __attribute__((address_space(1))) unsigned int*)gsrc,
          (__attribute__((address_space(3))) unsigned int*)(sm + OFF_SA + chunk * 1040), 16, 0, 0);
    }
  }

  for (; t < ntiles; t += NBLK) {
    const int tn = t + NBLK;
    const bool more = tn < ntiles;
    __syncthreads();  // (a) strips+A+O free; DMA(t) drained; params ready (1st iter)
    // ---------------- W: regs + strip -> bf16 A tile ----------------
    {
      char* a0 = sm + OFF_A + srow * 384;
      const int swz = (srow & 7) << 4;
      cvt8s(ga0, ga1, a0 + ((oct * 16) ^ swz));
      cvt8s(gb0, gb1, a0 + ((128 + oct * 16) ^ swz));
      const char* sa = sm + OFF_SA + (srow >> 2) * 1040 + (srow & 3) * 256 + oct * 32;
      float4 c0 = *(const float4*)sa, c1 = *(const float4*)(sa + 16);
      cvt8s(c0, c1, a0 + ((256 + oct * 16) ^ swz));
      if (EDGE && (tid & 7) == 0) ((int*)(sm + OFF_IX))[srow] = dcur;
    }
    int dn = 0, sn = 0;
    if (EDGE && more) {
      int row = tn * 64 + srow;
      int e = perm[row];
      dn = dstS[row]; sn = srcI[e];
    }
    __syncthreads();  // (b) A ready
    // ---------------- P: issue prefetch for tn ----------------
    if (more) {
      const float *p1, *p2;
      if (EDGE) {
        p1 = g1 + (size_t)dn * 64 + oct * 8;
        p2 = g2 + (size_t)sn * 64 + oct * 8;
        dcur = dn;
      } else {
        int rr = min(tn * 64 + srow, M - 1);
        p1 = g1 + (size_t)rr * 64 + oct * 8;
        p2 = g2 + (size_t)rr * 64 + oct * 8;
      }
      ga0 = *(const float4*)p1; ga1 = *(const float4*)(p1 + 4);
      gb0 = *(const float4*)p2; gb1 = *(const float4*)(p2 + 4);
#pragma unroll
      for (int i = 0; i < 2; ++i) {
        int chunk = wave * 2 + i;
        const float* gsrc;
        if (EDGE) {
          int er = perm[tn * 64 + chunk * 4 + (lane >> 4)];
          gsrc = g3 + (size_t)er * 64 + (lane & 15) * 4;
        } else { int gr = min(tn * 64 + chunk * 4 + (lane >> 4), M - 1); gsrc = g3 + (size_t)gr * 64 + (lane & 15) * 4; }
        __builtin_amdgcn_global_load_lds((const __attribute__((address_space(1))) unsigned int*)gsrc,
            (__attribute__((address_space(3))) unsigned int*)(sm + OFF_SA + chunk * 1040), 16, 0, 0);
      }
    }
    // ---------------- L0: A[192] -> H0[128], relu ----------------
    {
      const f32x4 bb0 = *(const f32x4*)(PAR + wave * 16 + cg * 4);
#pragma unroll
      for (int rt = 0; rt < 4; ++rt) {
        const int row = rt * 16 + lrow, swz = (row & 7) << 4;
        const char* ab = sm + OFF_A + row * 384;
        f32x4 acc = {0.f, 0.f, 0.f, 0.f};
#pragma unroll
        for (int kk = 0; kk < 6; ++kk)
          acc = MFMA(w0f[kk], *(const bf16x8*)(ab + ((kk * 64 + cg * 16) ^ swz)), acc);
        f32x4 h;
#pragma unroll
        for (int q = 0; q < 4; ++q) h[q] = fmaxf(acc[q] + bb0[q], 0.f);
        *(unsigned long long*)(sm + OFF_H0 + row * 256 + ((wave * 32 + cg * 8) ^ swz)) = pk4(h);
      }
    }
    __syncthreads();  // (c) H0 ready
    // ---------------- L1: H0 -> H1 (A[0,256) overlay), relu ----------------
    {
      const f32x4 bb1 = *(const f32x4*)(PAR + 128 + wave * 16 + cg * 4);
#pragma unroll
      for (int rt = 0; rt < 4; ++rt) {
        const int row = rt * 16 + lrow, swz = (row & 7) << 4;
        const char* hb = sm + OFF_H0 + row * 256;
        f32x4 acc = {0.f, 0.f, 0.f, 0.f};
#pragma unroll
        for (int kk = 0; kk < 4; ++kk)
          acc = MFMA(w1f[kk], *(const bf16x8*)(hb + ((kk * 64 + cg * 16) ^ swz)), acc);
        f32x4 h;
#pragma unroll
        for (int q = 0; q < 4; ++q) h[q] = fmaxf(acc[q] + bb1[q], 0.f);
        *(unsigned long long*)(sm + OFF_A + row * 384 + ((wave * 32 + cg * 8) ^ swz)) = pk4(h);
      }
    }
    __syncthreads();  // (d) H1 ready (H0/O region now free)
    // ---------------- L2p: H1 -> acc + bias, LN partials ----------------
    f32x4 accE[2];
    {
      const f32x4 bb2 = *(const f32x4*)(PAR + 256 + cg2 * 16 + cg * 4);
#pragma unroll
      for (int j = 0; j < 2; ++j) {
        const int rt = rg * 2 + j, row = rt * 16 + lrow, swz = (row & 7) << 4;
        const char* hb = sm + OFF_A + row * 384;
        f32x4 acc = {0.f, 0.f, 0.f, 0.f};
#pragma unroll
        for (int kk = 0; kk < 4; ++kk)
          acc = MFMA(w2f[kk], *(const bf16x8*)(hb + ((kk * 64 + cg * 16) ^ swz)), acc);
#pragma unroll
        for (int q = 0; q < 4; ++q) acc[q] += bb2[q];
        float s = acc[0] + acc[1] + acc[2] + acc[3];
        float ss = acc[0] * acc[0] + acc[1] * acc[1] + acc[2] * acc[2] + acc[3] * acc[3];
        s += __shfl_xor(s, 16, 64); s += __shfl_xor(s, 32, 64);
        ss += __shfl_xor(ss, 16, 64); ss += __shfl_xor(ss, 32, 64);
        if (cg == 0) *(float2*)(sm + OFF_P + row * 32 + cg2 * 8) = make_float2(s, ss);
        accE[j] = acc;
      }
    }
    __syncthreads();  // (e) partials ready
    // ---------------- E2: LN + residual -> O (fp32, swizzled) ----------------
    {
      const f32x4 gv = *(const f32x4*)(PAR + 320 + cg2 * 16 + cg * 4);
      const f32x4 bv = *(const f32x4*)(PAR + 384 + cg2 * 16 + cg * 4);
#pragma unroll
      for (int j = 0; j < 2; ++j) {
        const int rt = rg * 2 + j, row = rt * 16 + lrow;
        float4 p0 = *(const float4*)(sm + OFF_P + row * 32);
        float4 p1 = *(const float4*)(sm + OFF_P + row * 32 + 16);
        float s = p0.x + p0.z + p1.x + p1.z, ss = p0.y + p0.w + p1.y + p1.w;
        float mean = s * (1.f / 64.f);
        float var = fmaxf(ss * (1.f / 64.f) - mean * mean, 0.f);
        float inv = rsqrtf(var + 1e-5f);
        const int swz = (row & 7) << 4;
        unsigned long long rv =
            *(const unsigned long long*)(sm + OFF_A + row * 384 + ((256 + cg2 * 32 + cg * 8) ^ swz));
        f32x4 a = accE[j];
        f32x4 o;
        o[0] = (a[0] - mean) * inv * gv[0] + bv[0] + bf2f((unsigned short)rv);
        o[1] = (a[1] - mean) * inv * gv[1] + bv[1] + bf2f((unsigned short)(rv >> 16));
        o[2] = (a[2] - mean) * inv * gv[2] + bv[2] + bf2f((unsigned short)(rv >> 32));
        o[3] = (a[3] - mean) * inv * gv[3] + bv[3] + bf2f((unsigned short)(rv >> 48));
        *(f32x4*)(sm + OFF_O + row * 256 + ((cg2 * 64 + cg * 16) ^ ((row & 15) << 4))) = o;
      }
    }
    __syncthreads();  // (f) O ready
    // ---------------- WR: coalesced stores + segmented run-atomics ----------------
#pragma unroll
    for (int j = 0; j < 2; ++j) {
      const int row = wave * 8 + j * 4 + cg, gr = t * 64 + row;
      const int cq = lrow;
      f32x4 v = *(const f32x4*)(sm + OFF_O + row * 256 + ((cq * 16) ^ ((row & 15) << 4)));
      if (EDGE) {
        const int e = perm[gr];
        *(f32x4*)(outp + (size_t)e * 64 + cq * 4) = v;
        const int* ix = (const int*)(sm + OFF_IX);
        const int d = ix[row];
        const bool head = (row == 0) || (ix[row - 1] != d);
        if (head) {
          float a0, a1, a2, a3;
          {
            const int swz = (row & 15) << 4;
            a0 = *(const float*)(sm + OFF_O + row * 256 + ((cq * 4) ^ swz));
            a1 = *(const float*)(sm + OFF_O + row * 256 + (((cq + 16) * 4) ^ swz));
            a2 = *(const float*)(sm + OFF_O + row * 256 + (((cq + 32) * 4) ^ swz));
            a3 = *(const float*)(sm + OFF_O + row * 256 + (((cq + 48) * 4) ^ swz));
          }
          int r2 = row + 1;
          while (r2 < 64 && ix[r2] == d) {
            const int swz = (r2 & 15) << 4;
            a0 += *(const float*)(sm + OFF_O + r2 * 256 + ((cq * 4) ^ swz));
            a1 += *(const float*)(sm + OFF_O + r2 * 256 + (((cq + 16) * 4) ^ swz));
            a2 += *(const float*)(sm + OFF_O + r2 * 256 + (((cq + 32) * 4) ^ swz));
            a3 += *(const float*)(sm + OFF_O + r2 * 256 + (((cq + 48) * 4) ^ swz));
            ++r2;
          }
          float* ap = agg + (size_t)d * 64;
          atomicAdd(ap + cq, a0);
          atomicAdd(ap + cq + 16, a1);
          atomicAdd(ap + cq + 32, a2);
          atomicAdd(ap + cq + 48, a3);
        }
      } else {
        if (gr < M) *(f32x4*)(outp + (size_t)gr * 64 + cq * 4) = v;
      }
    }
  }
}

// ---- prep: transpose+cast weights to bf16 [out][in]; rotate upd-W0 rows by 64 ----
struct PrepArgs { const float* w[9]; unsigned short* wt[3]; };

__global__ void prep_w(PrepArgs pa) {
  int i = blockIdx.x * 256 + threadIdx.x;
  if (i >= 3 * 49152) return;
  int mlp = i / 49152;
  int rem = i - mlp * 49152;
  int mat, off, K, N;
  if (rem < 24576)      { mat = 0; off = 0;     K = 192; N = 128; }
  else if (rem < 40960) { mat = 1; off = 24576; K = 128; N = 128; }
  else                  { mat = 2; off = 40960; K = 128; N = 64;  }
  int local = rem - off;
  int n = local / K, k = local - n * K;
  if (mlp == 2 && mat == 0) k = (k + 64) % 192;  // concat rotation for node MLP
  pa.wt[mlp][rem] = f2bf(pa.w[mlp * 3 + mat][k * N + n]);
}

__global__ void zero_f4(float4* p, int n) {
  int i = blockIdx.x * blockDim.x + threadIdx.x;
  if (i < n) p[i] = make_float4(0.f, 0.f, 0.f, 0.f);
}

// ---- counting sort by dst: hist -> scan (in-place, per set) -> scatter ----
__global__ void hist_k(const int* __restrict__ dM, const int* __restrict__ dW,
                       int* __restrict__ curM, int* __restrict__ curW, int E) {
  int i = blockIdx.x * 256 + threadIdx.x;
  if (i < E) {
    atomicAdd(curM + dM[i], 1);
    atomicAdd(curW + dW[i], 1);
  }
}

__global__ __launch_bounds__(1024) void scan_k(int* __restrict__ curM, int* __restrict__ curW) {
  __shared__ int buf[1024];
  int* cur = blockIdx.x ? curW : curM;
  const int tid = threadIdx.x, base = tid * 49;
  const int lim = min(base + 49, NNODES);
  int p = 0;
  for (int b = base; b < lim; ++b) p += cur[b];
  buf[tid] = p;
  __syncthreads();
  const int own = p;
  for (int off = 1; off < 1024; off <<= 1) {
    int nv = (tid >= off) ? buf[tid - off] : 0;
    __syncthreads();
    buf[tid] += nv;
    __syncthreads();
  }
  int running = buf[tid] - own;  // exclusive prefix
  for (int b = base; b < lim; ++b) { int h = cur[b]; cur[b] = running; running += h; }
}

__global__ void scatter_k(const int* __restrict__ dM, const int* __restrict__ dW,
                          int* __restrict__ curM, int* __restrict__ curW,
                          int* __restrict__ permM, int* __restrict__ dstSM,
                          int* __restrict__ permW, int* __restrict__ dstSW, int E) {
  int i = blockIdx.x * 256 + threadIdx.x;
  if (i < E) {
    int d = dM[i];
    int p = atomicAdd(curM + d, 1);
    permM[p] = i; dstSM[p] = d;
    d = dW[i];
    p = atomicAdd(curW + d, 1);
    permW[p] = i; dstSW[p] = d;
  }
}

extern "C" void kernel_launch(void* const* d_in, const int* in_sizes, int n_in,
                              void* d_out, int out_size, void* d_ws, size_t ws_size,
                              hipStream_t stream) {
  const float* x      = (const float*)d_in[0];
  const int*   meIdx  = (const int*)d_in[1];
  const float* meAttr = (const float*)d_in[2];
  const int*   weIdx  = (const int*)d_in[3];
  const float* weAttr = (const float*)d_in[4];

  float* out_x  = (float*)d_out;
  float* out_em = out_x + (size_t)NNODES * 64;
  float* out_ew = out_em + (size_t)NEDGES * 64;

  char* ws = (char*)d_ws;
  unsigned short* WtM = (unsigned short*)ws;
  unsigned short* WtW = (unsigned short*)(ws + 98304);
  unsigned short* WtU = (unsigned short*)(ws + 196608);
  float* aggm = (float*)(ws + 294912);                 // 12.8 MB
  float* aggw = aggm + (size_t)NNODES * 64;            // 12.8 MB
  int* curM  = (int*)(ws + 294912 + 25600000);         // 200 KB
  int* curW  = curM + NNODES;                          // 200 KB
  int* permM = (int*)(ws + 294912 + 25600000 + 400000);
  int* dstSM = permM + NEDGES;
  int* permW = dstSM + NEDGES;
  int* dstSW = permW + NEDGES;                         // end ~39.1 MB

  // zero agg buffers + sort counters
  zero_f4<<<dim3(6250), dim3(256), 0, stream>>>((float4*)aggm, 1600000);
  zero_f4<<<dim3(98), dim3(256), 0, stream>>>((float4*)curM, 25000);

  PrepArgs pa;
  for (int m = 0; m < 3; ++m)
    for (int l = 0; l < 3; ++l)
      pa.w[m * 3 + l] = (const float*)d_in[5 + m * 8 + l * 2];
  pa.wt[0] = WtM; pa.wt[1] = WtW; pa.wt[2] = WtU;
  prep_w<<<dim3(576), dim3(256), 0, stream>>>(pa);

  // counting sort by dst for both edge sets
  hist_k<<<dim3(3125), dim3(256), 0, stream>>>(meIdx + NEDGES, weIdx + NEDGES, curM, curW, NEDGES);
  scan_k<<<dim3(2), dim3(1024), 0, stream>>>(curM, curW);
  scatter_k<<<dim3(3125), dim3(256), 0, stream>>>(meIdx + NEDGES, weIdx + NEDGES, curM, curW,
                                                  permM, dstSM, permW, dstSW, NEDGES);

  // mesh edges: x_i = x[dst], x_j = x[src]
  mlp_block<true><<<dim3(NBLK), dim3(512), 0, stream>>>(
      x, x, meAttr, meIdx, permM, dstSM, WtM,
      (const float*)d_in[6], (const float*)d_in[8], (const float*)d_in[10],
      (const float*)d_in[11], (const float*)d_in[12],
      out_em, aggm, NEDGES);
  // world edges
  mlp_block<true><<<dim3(NBLK), dim3(512), 0, stream>>>(
      x, x, weAttr, weIdx, permW, dstSW, WtW,
      (const float*)d_in[14], (const float*)d_in[16], (const float*)d_in[18],
      (const float*)d_in[19], (const float*)d_in[20],
      out_ew, aggw, NEDGES);
  // node update: A = [aggm | aggw | x], residual = x
  mlp_block<false><<<dim3(NBLK), dim3(512), 0, stream>>>(
      aggm, aggw, x, nullptr, nullptr, nullptr, WtU,
      (const float*)d_in[22], (const float*)d_in[24], (const float*)d_in[26],
      (const float*)d_in[27], (const float*)d_in[28],
      out_x, nullptr, NNODES);
}

// Round 7
// 1215.720 us; speedup vs baseline: 1.0449x; 1.0449x over previous
//
#include <hip/hip_runtime.h>

// InteractionNetwork — fused MFMA, transposed-product formulation + dst-sorted
// edges. Counting-sort gives perm/dstS/srcS; edge MLP runs in sorted order.
// Aggregation: 2-step shuffled segmented suffix-sum within each wave's 4-row
// group, heads issue atomics (parallel; replaces R6's serial run-walk).
// Staging: all three input rows reg-loaded and bf16-packed in the prefetch
// phase (no DMA strip) -> LDS 44KB -> 3 blocks/CU when regs <= 85.

#define NNODES 50000
#define NEDGES 800000
#define NBLK 768

typedef __bf16 bf16x8 __attribute__((ext_vector_type(8)));
typedef float f32x4 __attribute__((ext_vector_type(4)));
#define MFMA(a, b, c) __builtin_amdgcn_mfma_f32_16x16x32_bf16(a, b, c, 0, 0, 0)

// LDS map (bytes)
#define OFF_A 0       // [64 rows][192 bf16] stride 384, XOR-swizzled; [0,256) reused as H1; [256,384) = residual seg
#define OFF_H0 24576  // [64 rows][128 bf16] stride 256, XOR-swizzled; reused as O [64][64] f32 after L1
#define OFF_O OFF_H0
#define OFF_P 40960   // [64 rows][4 float2] partial (s,ss) = 2048
#define OFF_IX 43008  // [64] int sorted dst indices = 256
#define OFF_PAR 43264 // param block: b0[128] b1[128] b2[64] gam[64] bet[64] = 448 f32
#define SMEM 45056

__device__ __forceinline__ unsigned short f2bf(float f) {
  unsigned u = __builtin_bit_cast(unsigned, f);
  u = (u + 0x7fffu + ((u >> 16) & 1u)) >> 16;
  return (unsigned short)u;
}
__device__ __forceinline__ float bf2f(unsigned short h) {
  return __builtin_bit_cast(float, (unsigned)h << 16);
}
__device__ __forceinline__ unsigned long long pk4(f32x4 v) {
  union { unsigned short h[4]; unsigned long long u; } p;
  p.h[0] = f2bf(v[0]); p.h[1] = f2bf(v[1]); p.h[2] = f2bf(v[2]); p.h[3] = f2bf(v[3]);
  return p.u;
}
__device__ __forceinline__ int4 pk8(float4 a, float4 b) {
  union { unsigned short us[8]; int4 v; } u;
  u.us[0] = f2bf(a.x); u.us[1] = f2bf(a.y); u.us[2] = f2bf(a.z); u.us[3] = f2bf(a.w);
  u.us[4] = f2bf(b.x); u.us[5] = f2bf(b.y); u.us[6] = f2bf(b.z); u.us[7] = f2bf(b.w);
  return u.v;
}
__device__ __forceinline__ int4 ldpk(const float* p) {
  return pk8(*(const float4*)p, *(const float4*)(p + 4));
}

// EDGE: rows = sorted edges; A = [x[dst] | x[src] | attr] (all bf16-packed in
//       regs), resid = attr, shuffled segmented-merge atomics into agg,
//       out scattered via perm.
// NODE: A = [aggm | aggw | x], resid = x (seg2), no atomics.
template <bool EDGE>
__global__ __launch_bounds__(512, 4) void mlp_block(
    const float* __restrict__ g1, const float* __restrict__ g2,
    const float* __restrict__ g3, const int* __restrict__ srcI,
    const int* __restrict__ srcS, const int* __restrict__ perm,
    const int* __restrict__ dstS, const unsigned short* __restrict__ Wt,
    const float* __restrict__ b0, const float* __restrict__ b1,
    const float* __restrict__ b2, const float* __restrict__ gam,
    const float* __restrict__ bet, float* __restrict__ outp,
    float* __restrict__ agg, int M) {
  __shared__ __align__(16) char sm[SMEM];
  const int tid = threadIdx.x, lane = tid & 63, wave = tid >> 6;
  const int lrow = lane & 15, cg = lane >> 4;
  const unsigned short* Wt0 = Wt;
  const unsigned short* Wt1 = Wt + 24576;
  const unsigned short* Wt2 = Wt + 40960;
  const int ntiles = (M + 63) >> 6;

  const int cg2 = wave & 3, rg = wave >> 2;

  // ---- stage bias/LN params into LDS ----
  for (int i = tid; i < 448; i += 512) {
    float v;
    if (i < 128) v = b0[i];
    else if (i < 256) v = b1[i - 128];
    else if (i < 320) v = b2[i - 256];
    else if (i < 384) v = gam[i - 320];
    else v = bet[i - 384];
    ((float*)(sm + OFF_PAR))[i] = v;
  }
  const float* PAR = (const float*)(sm + OFF_PAR);

  // ---- persistent weight fragments, deduped ----
  bf16x8 w0f[6], w1f[4], w2f[4];
#pragma unroll
  for (int kk = 0; kk < 6; ++kk)
    w0f[kk] = *(const bf16x8*)(Wt0 + (wave * 16 + lrow) * 192 + kk * 32 + cg * 8);
#pragma unroll
  for (int kk = 0; kk < 4; ++kk)
    w1f[kk] = *(const bf16x8*)(Wt1 + (wave * 16 + lrow) * 128 + kk * 32 + cg * 8);
#pragma unroll
  for (int kk = 0; kk < 4; ++kk)
    w2f[kk] = *(const bf16x8*)(Wt2 + (cg2 * 16 + lrow) * 128 + kk * 32 + cg * 8);

  // staging map: row = (tid>>5)*4 + ((tid&31)>>3), float-octet oct = tid&7
  const int srow = (tid >> 5) * 4 + ((tid & 31) >> 3), oct = tid & 7;

  int t = blockIdx.x;
  if (t >= ntiles) return;

  // ---- prologue: load + bf16-pack tile t ----
  int4 pxd, pxs, pat;
  int dcur = 0;
  {
    int row = t * 64 + srow;
    if (EDGE) {
      int e = perm[row];
      dcur = dstS[row];
      int s = srcS ? srcS[row] : srcI[e];
      pxd = ldpk(g1 + (size_t)dcur * 64 + oct * 8);
      pxs = ldpk(g1 + (size_t)s * 64 + oct * 8);
      pat = ldpk(g3 + (size_t)e * 64 + oct * 8);
    } else {
      int rr = min(row, M - 1);
      pxd = ldpk(g1 + (size_t)rr * 64 + oct * 8);
      pxs = ldpk(g2 + (size_t)rr * 64 + oct * 8);
      pat = ldpk(g3 + (size_t)rr * 64 + oct * 8);
    }
  }

  for (; t < ntiles; t += NBLK) {
    const int tn = t + NBLK;
    const bool more = tn < ntiles;
    __syncthreads();  // (a) A+O free
    // ---------------- W: packed regs -> bf16 A tile ----------------
    {
      char* a0 = sm + OFF_A + srow * 384;
      const int swz = (srow & 7) << 4;
      *(int4*)(a0 + ((oct * 16) ^ swz)) = pxd;
      *(int4*)(a0 + ((128 + oct * 16) ^ swz)) = pxs;
      *(int4*)(a0 + ((256 + oct * 16) ^ swz)) = pat;
      if (EDGE && (tid & 7) == 0) ((int*)(sm + OFF_IX))[srow] = dcur;
    }
    int en = 0, dn = 0, sn = 0;
    if (EDGE && more) {
      int row = tn * 64 + srow;
      en = perm[row];
      dn = dstS[row];
      sn = srcS ? srcS[row] : srcI[en];
    }
    __syncthreads();  // (b) A ready
    // ---------------- P: prefetch + pack for tn ----------------
    if (more) {
      if (EDGE) {
        pxd = ldpk(g1 + (size_t)dn * 64 + oct * 8);
        pxs = ldpk(g1 + (size_t)sn * 64 + oct * 8);
        pat = ldpk(g3 + (size_t)en * 64 + oct * 8);
        dcur = dn;
      } else {
        int rr = min(tn * 64 + srow, M - 1);
        pxd = ldpk(g1 + (size_t)rr * 64 + oct * 8);
        pxs = ldpk(g2 + (size_t)rr * 64 + oct * 8);
        pat = ldpk(g3 + (size_t)rr * 64 + oct * 8);
      }
    }
    // ---------------- L0: A[192] -> H0[128], relu ----------------
    {
      const f32x4 bb0 = *(const f32x4*)(PAR + wave * 16 + cg * 4);
#pragma unroll
      for (int rt = 0; rt < 4; ++rt) {
        const int row = rt * 16 + lrow, swz = (row & 7) << 4;
        const char* ab = sm + OFF_A + row * 384;
        f32x4 acc = {0.f, 0.f, 0.f, 0.f};
#pragma unroll
        for (int kk = 0; kk < 6; ++kk)
          acc = MFMA(w0f[kk], *(const bf16x8*)(ab + ((kk * 64 + cg * 16) ^ swz)), acc);
        f32x4 h;
#pragma unroll
        for (int q = 0; q < 4; ++q) h[q] = fmaxf(acc[q] + bb0[q], 0.f);
        *(unsigned long long*)(sm + OFF_H0 + row * 256 + ((wave * 32 + cg * 8) ^ swz)) = pk4(h);
      }
    }
    __syncthreads();  // (c) H0 ready
    // ---------------- L1: H0 -> H1 (A[0,256) overlay), relu ----------------
    {
      const f32x4 bb1 = *(const f32x4*)(PAR + 128 + wave * 16 + cg * 4);
#pragma unroll
      for (int rt = 0; rt < 4; ++rt) {
        const int row = rt * 16 + lrow, swz = (row & 7) << 4;
        const char* hb = sm + OFF_H0 + row * 256;
        f32x4 acc = {0.f, 0.f, 0.f, 0.f};
#pragma unroll
        for (int kk = 0; kk < 4; ++kk)
          acc = MFMA(w1f[kk], *(const bf16x8*)(hb + ((kk * 64 + cg * 16) ^ swz)), acc);
        f32x4 h;
#pragma unroll
        for (int q = 0; q < 4; ++q) h[q] = fmaxf(acc[q] + bb1[q], 0.f);
        *(unsigned long long*)(sm + OFF_A + row * 384 + ((wave * 32 + cg * 8) ^ swz)) = pk4(h);
      }
    }
    __syncthreads();  // (d) H1 ready (H0/O region free)
    // ---------------- L2p: H1 -> acc + bias, LN partials ----------------
    f32x4 accE[2];
    {
      const f32x4 bb2 = *(const f32x4*)(PAR + 256 + cg2 * 16 + cg * 4);
#pragma unroll
      for (int j = 0; j < 2; ++j) {
        const int rt = rg * 2 + j, row = rt * 16 + lrow, swz = (row & 7) << 4;
        const char* hb = sm + OFF_A + row * 384;
        f32x4 acc = {0.f, 0.f, 0.f, 0.f};
#pragma unroll
        for (int kk = 0; kk < 4; ++kk)
          acc = MFMA(w2f[kk], *(const bf16x8*)(hb + ((kk * 64 + cg * 16) ^ swz)), acc);
#pragma unroll
        for (int q = 0; q < 4; ++q) acc[q] += bb2[q];
        float s = acc[0] + acc[1] + acc[2] + acc[3];
        float ss = acc[0] * acc[0] + acc[1] * acc[1] + acc[2] * acc[2] + acc[3] * acc[3];
        s += __shfl_xor(s, 16, 64); s += __shfl_xor(s, 32, 64);
        ss += __shfl_xor(ss, 16, 64); ss += __shfl_xor(ss, 32, 64);
        if (cg == 0) *(float2*)(sm + OFF_P + row * 32 + cg2 * 8) = make_float2(s, ss);
        accE[j] = acc;
      }
    }
    __syncthreads();  // (e) partials ready
    // ---------------- E2: LN + residual -> O (fp32, swizzled) ----------------
    {
      const f32x4 gv = *(const f32x4*)(PAR + 320 + cg2 * 16 + cg * 4);
      const f32x4 bv = *(const f32x4*)(PAR + 384 + cg2 * 16 + cg * 4);
#pragma unroll
      for (int j = 0; j < 2; ++j) {
        const int rt = rg * 2 + j, row = rt * 16 + lrow;
        float4 p0 = *(const float4*)(sm + OFF_P + row * 32);
        float4 p1 = *(const float4*)(sm + OFF_P + row * 32 + 16);
        float s = p0.x + p0.z + p1.x + p1.z, ss = p0.y + p0.w + p1.y + p1.w;
        float mean = s * (1.f / 64.f);
        float var = fmaxf(ss * (1.f / 64.f) - mean * mean, 0.f);
        float inv = rsqrtf(var + 1e-5f);
        const int swz = (row & 7) << 4;
        unsigned long long rv =
            *(const unsigned long long*)(sm + OFF_A + row * 384 + ((256 + cg2 * 32 + cg * 8) ^ swz));
        f32x4 a = accE[j];
        f32x4 o;
        o[0] = (a[0] - mean) * inv * gv[0] + bv[0] + bf2f((unsigned short)rv);
        o[1] = (a[1] - mean) * inv * gv[1] + bv[1] + bf2f((unsigned short)(rv >> 16));
        o[2] = (a[2] - mean) * inv * gv[2] + bv[2] + bf2f((unsigned short)(rv >> 32));
        o[3] = (a[3] - mean) * inv * gv[3] + bv[3] + bf2f((unsigned short)(rv >> 48));
        *(f32x4*)(sm + OFF_O + row * 256 + ((cg2 * 64 + cg * 16) ^ ((row & 15) << 4))) = o;
      }
    }
    __syncthreads();  // (f) O ready
    // ---------------- WR: stores + shuffled segmented-merge atomics ----------------
    {
      const int* ix = (const int*)(sm + OFF_IX);
#pragma unroll
      for (int j = 0; j < 2; ++j) {
        const int row = wave * 8 + j * 4 + cg, gr = t * 64 + row;
        const int cq = lrow;
        f32x4 v = *(const f32x4*)(sm + OFF_O + row * 256 + ((cq * 16) ^ ((row & 15) << 4)));
        if (EDGE) {
          const int e = perm[gr];
          *(f32x4*)(outp + (size_t)e * 64 + cq * 4) = v;
          const int d = ix[row];
          // segmented suffix-sum over the 4-row group (lanes differ by 16)
          {
            int d1 = __shfl_down(d, 16, 64);
            f32x4 vn;
#pragma unroll
            for (int q = 0; q < 4; ++q) vn[q] = __shfl_down(v[q], 16, 64);
            if (cg < 3 && d1 == d) {
#pragma unroll
              for (int q = 0; q < 4; ++q) v[q] += vn[q];
            }
            int d2 = __shfl_down(d, 32, 64);
#pragma unroll
            for (int q = 0; q < 4; ++q) vn[q] = __shfl_down(v[q], 32, 64);
            if (cg < 2 && d2 == d) {
#pragma unroll
              for (int q = 0; q < 4; ++q) v[q] += vn[q];
            }
          }
          const bool issue = (cg == 0) || (ix[row - 1] != d);
          if (issue) {
            float* ap = agg + (size_t)d * 64 + cq * 4;
            atomicAdd(ap, v[0]);
            atomicAdd(ap + 1, v[1]);
            atomicAdd(ap + 2, v[2]);
            atomicAdd(ap + 3, v[3]);
          }
        } else {
          if (gr < M) *(f32x4*)(outp + (size_t)gr * 64 + cq * 4) = v;
        }
      }
    }
  }
}

// ---- prep: transpose+cast weights to bf16 [out][in]; rotate upd-W0 rows by 64 ----
struct PrepArgs { const float* w[9]; unsigned short* wt[3]; };

__global__ void prep_w(PrepArgs pa) {
  int i = blockIdx.x * 256 + threadIdx.x;
  if (i >= 3 * 49152) return;
  int mlp = i / 49152;
  int rem = i - mlp * 49152;
  int mat, off, K, N;
  if (rem < 24576)      { mat = 0; off = 0;     K = 192; N = 128; }
  else if (rem < 40960) { mat = 1; off = 24576; K = 128; N = 128; }
  else                  { mat = 2; off = 40960; K = 128; N = 64;  }
  int local = rem - off;
  int n = local / K, k = local - n * K;
  if (mlp == 2 && mat == 0) k = (k + 64) % 192;  // concat rotation for node MLP
  pa.wt[mlp][rem] = f2bf(pa.w[mlp * 3 + mat][k * N + n]);
}

__global__ void zero_f4(float4* p, int n) {
  int i = blockIdx.x * blockDim.x + threadIdx.x;
  if (i < n) p[i] = make_float4(0.f, 0.f, 0.f, 0.f);
}

// ---- counting sort by dst: hist -> scan (in-place, per set) -> scatter ----
__global__ void hist_k(const int* __restrict__ dM, const int* __restrict__ dW,
                       int* __restrict__ curM, int* __restrict__ curW, int E) {
  int i = blockIdx.x * 256 + threadIdx.x;
  if (i < E) {
    atomicAdd(curM + dM[i], 1);
    atomicAdd(curW + dW[i], 1);
  }
}

__global__ __launch_bounds__(1024) void scan_k(int* __restrict__ curM, int* __restrict__ curW) {
  __shared__ int buf[1024];
  int* cur = blockIdx.x ? curW : curM;
  const int tid = threadIdx.x, base = tid * 49;
  const int lim = min(base + 49, NNODES);
  int p = 0;
  for (int b = base; b < lim; ++b) p += cur[b];
  buf[tid] = p;
  __syncthreads();
  const int own = p;
  for (int off = 1; off < 1024; off <<= 1) {
    int nv = (tid >= off) ? buf[tid - off] : 0;
    __syncthreads();
    buf[tid] += nv;
    __syncthreads();
  }
  int running = buf[tid] - own;  // exclusive prefix
  for (int b = base; b < lim; ++b) { int h = cur[b]; cur[b] = running; running += h; }
}

__global__ void scatter_k(const int* __restrict__ dM, const int* __restrict__ dW,
                          const int* __restrict__ sM, const int* __restrict__ sW,
                          int* __restrict__ curM, int* __restrict__ curW,
                          int* __restrict__ permM, int* __restrict__ dstSM,
                          int* __restrict__ permW, int* __restrict__ dstSW,
                          int* __restrict__ srcSM, int* __restrict__ srcSW, int E) {
  int i = blockIdx.x * 256 + threadIdx.x;
  if (i < E) {
    int d = dM[i];
    int p = atomicAdd(curM + d, 1);
    permM[p] = i; dstSM[p] = d;
    if (srcSM) srcSM[p] = sM[i];
    d = dW[i];
    p = atomicAdd(curW + d, 1);
    permW[p] = i; dstSW[p] = d;
    if (srcSW) srcSW[p] = sW[i];
  }
}

extern "C" void kernel_launch(void* const* d_in, const int* in_sizes, int n_in,
                              void* d_out, int out_size, void* d_ws, size_t ws_size,
                              hipStream_t stream) {
  const float* x      = (const float*)d_in[0];
  const int*   meIdx  = (const int*)d_in[1];
  const float* meAttr = (const float*)d_in[2];
  const int*   weIdx  = (const int*)d_in[3];
  const float* weAttr = (const float*)d_in[4];

  float* out_x  = (float*)d_out;
  float* out_em = out_x + (size_t)NNODES * 64;
  float* out_ew = out_em + (size_t)NEDGES * 64;

  char* ws = (char*)d_ws;
  unsigned short* WtM = (unsigned short*)ws;
  unsigned short* WtW = (unsigned short*)(ws + 98304);
  unsigned short* WtU = (unsigned short*)(ws + 196608);
  float* aggm = (float*)(ws + 294912);                 // 12.8 MB
  float* aggw = aggm + (size_t)NNODES * 64;            // 12.8 MB
  char* p = ws + 294912 + 25600000;
  int* curM  = (int*)p;                                // 200 KB
  int* curW  = curM + NNODES;                          // 200 KB
  int* permM = (int*)(p + 400000);
  int* dstSM = permM + NEDGES;
  int* permW = dstSM + NEDGES;
  int* dstSW = permW + NEDGES;                         // end 39.1 MB
  const bool full = ws_size >= (size_t)(294912 + 25600000 + 400000 + 6 * 3200000);
  int* srcSM = full ? (dstSW + NEDGES) : nullptr;
  int* srcSW = full ? (srcSM + NEDGES) : nullptr;

  // zero agg buffers + sort counters
  zero_f4<<<dim3(6250), dim3(256), 0, stream>>>((float4*)aggm, 1600000);
  zero_f4<<<dim3(98), dim3(256), 0, stream>>>((float4*)curM, 25000);

  PrepArgs pa;
  for (int m = 0; m < 3; ++m)
    for (int l = 0; l < 3; ++l)
      pa.w[m * 3 + l] = (const float*)d_in[5 + m * 8 + l * 2];
  pa.wt[0] = WtM; pa.wt[1] = WtW; pa.wt[2] = WtU;
  prep_w<<<dim3(576), dim3(256), 0, stream>>>(pa);

  // counting sort by dst for both edge sets (+ sorted src)
  hist_k<<<dim3(3125), dim3(256), 0, stream>>>(meIdx + NEDGES, weIdx + NEDGES, curM, curW, NEDGES);
  scan_k<<<dim3(2), dim3(1024), 0, stream>>>(curM, curW);
  scatter_k<<<dim3(3125), dim3(256), 0, stream>>>(meIdx + NEDGES, weIdx + NEDGES,
                                                  meIdx, weIdx, curM, curW,
                                                  permM, dstSM, permW, dstSW,
                                                  srcSM, srcSW, NEDGES);

  // mesh edges: x_i = x[dst], x_j = x[src]
  mlp_block<true><<<dim3(NBLK), dim3(512), 0, stream>>>(
      x, x, meAttr, meIdx, srcSM, permM, dstSM, WtM,
      (const float*)d_in[6], (const float*)d_in[8], (const float*)d_in[10],
      (const float*)d_in[11], (const float*)d_in[12],
      out_em, aggm, NEDGES);
  // world edges
  mlp_block<true><<<dim3(NBLK), dim3(512), 0, stream>>>(
      x, x, weAttr, weIdx, srcSW, permW, dstSW, WtW,
      (const float*)d_in[14], (const float*)d_in[16], (const float*)d_in[18],
      (const float*)d_in[19], (const float*)d_in[20],
      out_ew, aggw, NEDGES);
  // node update: A = [aggm | aggw | x], residual = x
  mlp_block<false><<<dim3(NBLK), dim3(512), 0, stream>>>(
      aggm, aggw, x, nullptr, nullptr, nullptr, nullptr, WtU,
      (const float*)d_in[22], (const float*)d_in[24], (const float*)d_in[26],
      (const float*)d_in[27], (const float*)d_in[28],
      out_x, nullptr, NNODES);
}

// Round 8
// 931.453 us; speedup vs baseline: 1.3637x; 1.3052x over previous
//
#include <hip/hip_runtime.h>

// InteractionNetwork — decomposed:
//   K_mlp  : edge/node MLP+LN, original order, no atomics, direct stores.
//   K_agg  : CSR segment-sum (counting-sorted perm/rowptr), one wave/node.
//   sort   : hist -> scan(rowptr) -> scatter(perm).
// MLP: OUT^T = W^T * X^T, weight frags persistent+deduped in regs, activations
// through XOR-swizzled LDS, 4 barriers/tile, residual re-read from global.

#define NNODES 50000
#define NEDGES 800000
#define NBLK 512

typedef __bf16 bf16x8 __attribute__((ext_vector_type(8)));
typedef float f32x4 __attribute__((ext_vector_type(4)));
#define MFMA(a, b, c) __builtin_amdgcn_mfma_f32_16x16x32_bf16(a, b, c, 0, 0, 0)

// LDS map (bytes)
#define OFF_A 0       // [64][192] bf16 stride 384, swizzled; [0,256) reused as H1
#define OFF_H0 24576  // [64][128] bf16 stride 256, swizzled
#define OFF_P 40960   // [64 rows][4 float2] (s,ss) partials
#define OFF_PAR 43008 // b0[128] b1[128] b2[64] gam[64] bet[64] = 448 f32
#define SMEM 44800

__device__ __forceinline__ unsigned short f2bf(float f) {
  unsigned u = __builtin_bit_cast(unsigned, f);
  u = (u + 0x7fffu + ((u >> 16) & 1u)) >> 16;
  return (unsigned short)u;
}
__device__ __forceinline__ unsigned long long pk4(f32x4 v) {
  union { unsigned short h[4]; unsigned long long u; } p;
  p.h[0] = f2bf(v[0]); p.h[1] = f2bf(v[1]); p.h[2] = f2bf(v[2]); p.h[3] = f2bf(v[3]);
  return p.u;
}
__device__ __forceinline__ int4 pk8(float4 a, float4 b) {
  union { unsigned short us[8]; int4 v; } u;
  u.us[0] = f2bf(a.x); u.us[1] = f2bf(a.y); u.us[2] = f2bf(a.z); u.us[3] = f2bf(a.w);
  u.us[4] = f2bf(b.x); u.us[5] = f2bf(b.y); u.us[6] = f2bf(b.z); u.us[7] = f2bf(b.w);
  return u.v;
}
__device__ __forceinline__ int4 ldpk(const float* p) {
  return pk8(*(const float4*)p, *(const float4*)(p + 4));
}

// EDGE: A = [x[dst] | x[src] | attr], residual = attr = g3[row]. out = original order.
// NODE: A = [aggm | aggw | x],       residual = x    = g3[row]. (W0 pre-rotated.)
template <bool EDGE>
__global__ __launch_bounds__(512, 4) void mlp_block(
    const float* __restrict__ g1, const float* __restrict__ g2,
    const float* __restrict__ g3, const int* __restrict__ srcI,
    const int* __restrict__ dstI, const unsigned short* __restrict__ Wt,
    const float* __restrict__ b0, const float* __restrict__ b1,
    const float* __restrict__ b2, const float* __restrict__ gam,
    const float* __restrict__ bet, float* __restrict__ outp, int M) {
  __shared__ __align__(16) char sm[SMEM];
  const int tid = threadIdx.x, lane = tid & 63, wave = tid >> 6;
  const int lrow = lane & 15, cg = lane >> 4;
  const unsigned short* Wt0 = Wt;
  const unsigned short* Wt1 = Wt + 24576;
  const unsigned short* Wt2 = Wt + 40960;
  const int ntiles = (M + 63) >> 6;
  const int cg2 = wave & 3, rg = wave >> 2;

  // ---- stage bias/LN params into LDS ----
  for (int i = tid; i < 448; i += 512) {
    float v;
    if (i < 128) v = b0[i];
    else if (i < 256) v = b1[i - 128];
    else if (i < 320) v = b2[i - 256];
    else if (i < 384) v = gam[i - 320];
    else v = bet[i - 384];
    ((float*)(sm + OFF_PAR))[i] = v;
  }
  const float* PAR = (const float*)(sm + OFF_PAR);

  // ---- persistent weight fragments, deduped across waves ----
  bf16x8 w0f[6], w1f[4], w2f[4];
#pragma unroll
  for (int kk = 0; kk < 6; ++kk)
    w0f[kk] = *(const bf16x8*)(Wt0 + (wave * 16 + lrow) * 192 + kk * 32 + cg * 8);
#pragma unroll
  for (int kk = 0; kk < 4; ++kk)
    w1f[kk] = *(const bf16x8*)(Wt1 + (wave * 16 + lrow) * 128 + kk * 32 + cg * 8);
#pragma unroll
  for (int kk = 0; kk < 4; ++kk)
    w2f[kk] = *(const bf16x8*)(Wt2 + (cg2 * 16 + lrow) * 128 + kk * 32 + cg * 8);

  // staging map: row = (tid>>5)*4 + ((tid&31)>>3), float-octet oct = tid&7
  const int srow = (tid >> 5) * 4 + ((tid & 31) >> 3), oct = tid & 7;

  int4 pxd, pxs, pat;
  auto LOADT = [&](int tt) {
    const int row = tt * 64 + srow;
    if (EDGE) {
      const int d = dstI[row], s = srcI[row];
      pxd = ldpk(g1 + (size_t)d * 64 + oct * 8);
      pxs = ldpk(g1 + (size_t)s * 64 + oct * 8);
      pat = ldpk(g3 + (size_t)row * 64 + oct * 8);
    } else {
      const int rr = min(row, M - 1);
      pxd = ldpk(g1 + (size_t)rr * 64 + oct * 8);
      pxs = ldpk(g2 + (size_t)rr * 64 + oct * 8);
      pat = ldpk(g3 + (size_t)rr * 64 + oct * 8);
    }
  };
  auto STAGE = [&]() {
    char* a0 = sm + OFF_A + srow * 384;
    const int swz = (srow & 7) << 4;
    *(int4*)(a0 + ((oct * 16) ^ swz)) = pxd;
    *(int4*)(a0 + ((128 + oct * 16) ^ swz)) = pxs;
    *(int4*)(a0 + ((256 + oct * 16) ^ swz)) = pat;
  };

  int t = blockIdx.x;
  if (t >= ntiles) return;
  LOADT(t);
  STAGE();

  for (; t < ntiles; t += NBLK) {
    const int tn = t + NBLK;
    const bool more = tn < ntiles;
    __syncthreads();  // (a) A(t) + PAR visible
    if (more) LOADT(tn);  // issue next-tile global loads under the MFMA phases
    // ---------------- L0: A[192] -> H0[128], relu ----------------
    {
      const f32x4 bb0 = *(const f32x4*)(PAR + wave * 16 + cg * 4);
#pragma unroll
      for (int rt = 0; rt < 4; ++rt) {
        const int row = rt * 16 + lrow, swz = (row & 7) << 4;
        const char* ab = sm + OFF_A + row * 384;
        f32x4 acc = {0.f, 0.f, 0.f, 0.f};
#pragma unroll
        for (int kk = 0; kk < 6; ++kk)
          acc = MFMA(w0f[kk], *(const bf16x8*)(ab + ((kk * 64 + cg * 16) ^ swz)), acc);
        f32x4 h;
#pragma unroll
        for (int q = 0; q < 4; ++q) h[q] = fmaxf(acc[q] + bb0[q], 0.f);
        *(unsigned long long*)(sm + OFF_H0 + row * 256 + ((wave * 32 + cg * 8) ^ swz)) = pk4(h);
      }
    }
    __syncthreads();  // (c) H0 ready
    // ---------------- L1: H0 -> H1 (A[0,256) overlay), relu ----------------
    {
      const f32x4 bb1 = *(const f32x4*)(PAR + 128 + wave * 16 + cg * 4);
#pragma unroll
      for (int rt = 0; rt < 4; ++rt) {
        const int row = rt * 16 + lrow, swz = (row & 7) << 4;
        const char* hb = sm + OFF_H0 + row * 256;
        f32x4 acc = {0.f, 0.f, 0.f, 0.f};
#pragma unroll
        for (int kk = 0; kk < 4; ++kk)
          acc = MFMA(w1f[kk], *(const bf16x8*)(hb + ((kk * 64 + cg * 16) ^ swz)), acc);
        f32x4 h;
#pragma unroll
        for (int q = 0; q < 4; ++q) h[q] = fmaxf(acc[q] + bb1[q], 0.f);
        *(unsigned long long*)(sm + OFF_A + row * 384 + ((wave * 32 + cg * 8) ^ swz)) = pk4(h);
      }
    }
    __syncthreads();  // (d) H1 ready
    // ---------------- L2p: H1 -> acc + bias, LN partials ----------------
    f32x4 accE[2];
    {
      const f32x4 bb2 = *(const f32x4*)(PAR + 256 + cg2 * 16 + cg * 4);
#pragma unroll
      for (int j = 0; j < 2; ++j) {
        const int row = (rg * 2 + j) * 16 + lrow, swz = (row & 7) << 4;
        const char* hb = sm + OFF_A + row * 384;
        f32x4 acc = {0.f, 0.f, 0.f, 0.f};
#pragma unroll
        for (int kk = 0; kk < 4; ++kk)
          acc = MFMA(w2f[kk], *(const bf16x8*)(hb + ((kk * 64 + cg * 16) ^ swz)), acc);
#pragma unroll
        for (int q = 0; q < 4; ++q) acc[q] += bb2[q];
        float s = acc[0] + acc[1] + acc[2] + acc[3];
        float ss = acc[0] * acc[0] + acc[1] * acc[1] + acc[2] * acc[2] + acc[3] * acc[3];
        s += __shfl_xor(s, 16, 64); s += __shfl_xor(s, 32, 64);
        ss += __shfl_xor(ss, 16, 64); ss += __shfl_xor(ss, 32, 64);
        if (cg == 0) *(float2*)(sm + OFF_P + row * 32 + cg2 * 8) = make_float2(s, ss);
        accE[j] = acc;
      }
    }
    __syncthreads();  // (e) partials ready; H1 reads done -> A free for stage
    // ---------------- epilogue: LN + residual(global) + direct store ----------------
    {
      const f32x4 gv = *(const f32x4*)(PAR + 320 + cg2 * 16 + cg * 4);
      const f32x4 bv = *(const f32x4*)(PAR + 384 + cg2 * 16 + cg * 4);
#pragma unroll
      for (int j = 0; j < 2; ++j) {
        const int row = (rg * 2 + j) * 16 + lrow, gr = t * 64 + row;
        float4 p0 = *(const float4*)(sm + OFF_P + row * 32);
        float4 p1 = *(const float4*)(sm + OFF_P + row * 32 + 16);
        float s = p0.x + p0.z + p1.x + p1.z, ss = p0.y + p0.w + p1.y + p1.w;
        float mean = s * (1.f / 64.f);
        float var = fmaxf(ss * (1.f / 64.f) - mean * mean, 0.f);
        float inv = rsqrtf(var + 1e-5f);
        const int col = cg2 * 16 + cg * 4;
        const int grc = EDGE ? gr : min(gr, M - 1);
        const f32x4 r = *(const f32x4*)(g3 + (size_t)grc * 64 + col);
        f32x4 a = accE[j], o;
#pragma unroll
        for (int q = 0; q < 4; ++q) o[q] = (a[q] - mean) * inv * gv[q] + bv[q] + r[q];
        if (EDGE || gr < M) *(f32x4*)(outp + (size_t)gr * 64 + col) = o;
      }
    }
    if (more) STAGE();  // write next tile's A (loads complete via reg dependency)
  }
}

// ---- K_agg: CSR segment-sum, one wave per node ----
__global__ __launch_bounds__(256) void agg_k(const float* __restrict__ oute,
                                             const int* __restrict__ perm,
                                             const int* __restrict__ rp,
                                             float* __restrict__ agg) {
  const int lane = threadIdx.x & 63;
  const int r4 = lane >> 4, cq = lane & 15;
  const int w = (blockIdx.x * 256 + threadIdx.x) >> 6;
  const int nw = gridDim.x * 4;
  for (int d = w; d < NNODES; d += nw) {
    const int s = rp[d], e = rp[d + 1];
    f32x4 acc = {0.f, 0.f, 0.f, 0.f};
    for (int j = s + r4; j < e; j += 4) {
      const int row = perm[j];
      const f32x4 v = *(const f32x4*)(oute + (size_t)row * 64 + cq * 4);
#pragma unroll
      for (int q = 0; q < 4; ++q) acc[q] += v[q];
    }
#pragma unroll
    for (int q = 0; q < 4; ++q) {
      acc[q] += __shfl_xor(acc[q], 16, 64);
      acc[q] += __shfl_xor(acc[q], 32, 64);
    }
    if (r4 == 0) *(f32x4*)(agg + (size_t)d * 64 + cq * 4) = acc;
  }
}

// ---- prep: transpose+cast weights to bf16 [out][in]; rotate upd-W0 rows ----
struct PrepArgs { const float* w[9]; unsigned short* wt[3]; };

__global__ void prep_w(PrepArgs pa) {
  int i = blockIdx.x * 256 + threadIdx.x;
  if (i >= 3 * 49152) return;
  int mlp = i / 49152;
  int rem = i - mlp * 49152;
  int mat, off, K, N;
  if (rem < 24576)      { mat = 0; off = 0;     K = 192; N = 128; }
  else if (rem < 40960) { mat = 1; off = 24576; K = 128; N = 128; }
  else                  { mat = 2; off = 40960; K = 128; N = 64;  }
  int local = rem - off;
  int n = local / K, k = local - n * K;
  if (mlp == 2 && mat == 0) k = (k + 64) % 192;  // node concat [aggm|aggw|x]
  pa.wt[mlp][rem] = f2bf(pa.w[mlp * 3 + mat][k * N + n]);
}

__global__ void zero_f4(float4* p, int n) {
  int i = blockIdx.x * blockDim.x + threadIdx.x;
  if (i < n) p[i] = make_float4(0.f, 0.f, 0.f, 0.f);
}

// ---- counting sort by dst: hist -> scan(rowptr) -> scatter(perm) ----
__global__ void hist_k(const int* __restrict__ dM, const int* __restrict__ dW,
                       int* __restrict__ curM, int* __restrict__ curW, int E) {
  int i = blockIdx.x * 256 + threadIdx.x;
  if (i < E) {
    atomicAdd(curM + dM[i], 1);
    atomicAdd(curW + dW[i], 1);
  }
}

__global__ __launch_bounds__(1024) void scan_k(int* __restrict__ curM, int* __restrict__ curW,
                                               int* __restrict__ rpM, int* __restrict__ rpW) {
  __shared__ int buf[1024];
  int* cur = blockIdx.x ? curW : curM;
  int* rp = blockIdx.x ? rpW : rpM;
  const int tid = threadIdx.x, base = tid * 49;
  const int lim = min(base + 49, NNODES);
  int p = 0;
  for (int b = base; b < lim; ++b) p += cur[b];
  buf[tid] = p;
  __syncthreads();
  const int own = p;
  for (int off = 1; off < 1024; off <<= 1) {
    int nv = (tid >= off) ? buf[tid - off] : 0;
    __syncthreads();
    buf[tid] += nv;
    __syncthreads();
  }
  int running = buf[tid] - own;  // exclusive prefix
  for (int b = base; b < lim; ++b) {
    int h = cur[b];
    cur[b] = running;
    rp[b] = running;
    running += h;
  }
  if (tid == 1023) rp[NNODES] = buf[1023];
}

__global__ void scatter_k(const int* __restrict__ dM, const int* __restrict__ dW,
                          int* __restrict__ curM, int* __restrict__ curW,
                          int* __restrict__ permM, int* __restrict__ permW, int E) {
  int i = blockIdx.x * 256 + threadIdx.x;
  if (i < E) {
    int p = atomicAdd(curM + dM[i], 1);
    permM[p] = i;
    p = atomicAdd(curW + dW[i], 1);
    permW[p] = i;
  }
}

extern "C" void kernel_launch(void* const* d_in, const int* in_sizes, int n_in,
                              void* d_out, int out_size, void* d_ws, size_t ws_size,
                              hipStream_t stream) {
  const float* x      = (const float*)d_in[0];
  const int*   meIdx  = (const int*)d_in[1];
  const float* meAttr = (const float*)d_in[2];
  const int*   weIdx  = (const int*)d_in[3];
  const float* weAttr = (const float*)d_in[4];

  float* out_x  = (float*)d_out;
  float* out_em = out_x + (size_t)NNODES * 64;
  float* out_ew = out_em + (size_t)NEDGES * 64;

  char* ws = (char*)d_ws;
  unsigned short* WtM = (unsigned short*)ws;
  unsigned short* WtW = (unsigned short*)(ws + 98304);
  unsigned short* WtU = (unsigned short*)(ws + 196608);
  float* aggm = (float*)(ws + 294912);                   // 12.8 MB
  float* aggw = aggm + (size_t)NNODES * 64;              // 12.8 MB
  char* p = ws + 294912 + 25600000;
  int* curM  = (int*)p;                                  // 200 KB
  int* curW  = curM + NNODES;                            // 200 KB
  int* rpM   = (int*)(p + 400000);                       // 50016 ints
  int* rpW   = rpM + 50016;
  int* permM = rpW + 50016;                              // 3.2 MB
  int* permW = permM + NEDGES;                           // end ~33.1 MB

  zero_f4<<<dim3(98), dim3(256), 0, stream>>>((float4*)curM, 25000);

  PrepArgs pa;
  for (int m = 0; m < 3; ++m)
    for (int l = 0; l < 3; ++l)
      pa.w[m * 3 + l] = (const float*)d_in[5 + m * 8 + l * 2];
  pa.wt[0] = WtM; pa.wt[1] = WtW; pa.wt[2] = WtU;
  prep_w<<<dim3(576), dim3(256), 0, stream>>>(pa);

  hist_k<<<dim3(3125), dim3(256), 0, stream>>>(meIdx + NEDGES, weIdx + NEDGES, curM, curW, NEDGES);
  scan_k<<<dim3(2), dim3(1024), 0, stream>>>(curM, curW, rpM, rpW);
  scatter_k<<<dim3(3125), dim3(256), 0, stream>>>(meIdx + NEDGES, weIdx + NEDGES,
                                                  curM, curW, permM, permW, NEDGES);

  // edge MLPs (original order; x_i = x[dst], x_j = x[src])
  mlp_block<true><<<dim3(NBLK), dim3(512), 0, stream>>>(
      x, x, meAttr, meIdx, meIdx + NEDGES, WtM,
      (const float*)d_in[6], (const float*)d_in[8], (const float*)d_in[10],
      (const float*)d_in[11], (const float*)d_in[12],
      out_em, NEDGES);
  mlp_block<true><<<dim3(NBLK), dim3(512), 0, stream>>>(
      x, x, weAttr, weIdx, weIdx + NEDGES, WtW,
      (const float*)d_in[14], (const float*)d_in[16], (const float*)d_in[18],
      (const float*)d_in[19], (const float*)d_in[20],
      out_ew, NEDGES);

  // CSR segment sums
  agg_k<<<dim3(1024), dim3(256), 0, stream>>>(out_em, permM, rpM, aggm);
  agg_k<<<dim3(1024), dim3(256), 0, stream>>>(out_ew, permW, rpW, aggw);

  // node update: A = [aggm | aggw | x], residual = x
  mlp_block<false><<<dim3(NBLK), dim3(512), 0, stream>>>(
      aggm, aggw, x, nullptr, nullptr, WtU,
      (const float*)d_in[22], (const float*)d_in[24], (const float*)d_in[26],
      (const float*)d_in[27], (const float*)d_in[28],
      out_x, NNODES);
}

// Round 9
// 922.893 us; speedup vs baseline: 1.3764x; 1.0093x over previous
//
#include <hip/hip_runtime.h>

// InteractionNetwork — decomposed:
//   prep_x : x -> bf16 table xb (6.4 MB) so edge gathers read 128B rows.
//   K_mlp  : edge (both sets, one dispatch) / node MLP+LN, no atomics.
//   K_agg  : CSR segment-sum, both sets in one dispatch, perm lookahead.
//   sort   : hist -> scan(rowptr) -> scatter(perm).
// MLP: OUT^T = W^T * X^T, weight frags persistent+deduped in regs, activations
// through XOR-swizzled LDS, 4 barriers/tile, residual re-read from global (L2).

#define NNODES 50000
#define NEDGES 800000
#define NBLK 512

typedef __bf16 bf16x8 __attribute__((ext_vector_type(8)));
typedef float f32x4 __attribute__((ext_vector_type(4)));
#define MFMA(a, b, c) __builtin_amdgcn_mfma_f32_16x16x32_bf16(a, b, c, 0, 0, 0)

// LDS map (bytes)
#define OFF_A 0       // [64][192] bf16 stride 384, swizzled; [0,256) reused as H1
#define OFF_H0 24576  // [64][128] bf16 stride 256, swizzled
#define OFF_P 40960   // [64 rows][4 float2] (s,ss) partials
#define OFF_PAR 43008 // b0[128] b1[128] b2[64] gam[64] bet[64] = 448 f32
#define SMEM 44800

__device__ __forceinline__ unsigned short f2bf(float f) {
  unsigned u = __builtin_bit_cast(unsigned, f);
  u = (u + 0x7fffu + ((u >> 16) & 1u)) >> 16;
  return (unsigned short)u;
}
__device__ __forceinline__ unsigned long long pk4(f32x4 v) {
  union { unsigned short h[4]; unsigned long long u; } p;
  p.h[0] = f2bf(v[0]); p.h[1] = f2bf(v[1]); p.h[2] = f2bf(v[2]); p.h[3] = f2bf(v[3]);
  return p.u;
}
__device__ __forceinline__ int4 pk8(float4 a, float4 b) {
  union { unsigned short us[8]; int4 v; } u;
  u.us[0] = f2bf(a.x); u.us[1] = f2bf(a.y); u.us[2] = f2bf(a.z); u.us[3] = f2bf(a.w);
  u.us[4] = f2bf(b.x); u.us[5] = f2bf(b.y); u.us[6] = f2bf(b.z); u.us[7] = f2bf(b.w);
  return u.v;
}
__device__ __forceinline__ int4 ldpk(const float* p) {
  return pk8(*(const float4*)p, *(const float4*)(p + 4));
}

struct MArgs {
  const float* g1[2];              // node: aggm (edge: unused)
  const float* g2[2];              // node: aggw (edge: unused)
  const float* attrf[2];           // edge: attr (staging seg2 + residual); node: x (residual)
  const unsigned short* xb;        // bf16 x table
  const int* src[2];
  const int* dst[2];
  const unsigned short* Wt[2];
  const float* b0[2]; const float* b1[2]; const float* b2[2];
  const float* gm[2]; const float* bt[2];
  float* outp[2];
};

// EDGE: A = [xb[dst] | xb[src] | attr], residual = attr. Two sets per dispatch.
// NODE: A = [aggm | aggw | xb],        residual = x. (W0 pre-rotated.)
template <bool EDGE>
__global__ __launch_bounds__(512, 4) void mlp_block(MArgs a, int M) {
  __shared__ __align__(16) char sm[SMEM];
  const int set = EDGE ? (int)(blockIdx.x >= NBLK) : 0;
  const int bid0 = blockIdx.x - set * NBLK;
  const float* g1 = a.g1[set];
  const float* g2 = a.g2[set];
  const float* attrf = a.attrf[set];
  const unsigned short* xb = a.xb;
  const int* srcI = a.src[set];
  const int* dstI = a.dst[set];
  const unsigned short* Wt = a.Wt[set];
  float* outp = a.outp[set];

  const int tid = threadIdx.x, lane = tid & 63, wave = tid >> 6;
  const int lrow = lane & 15, cg = lane >> 4;
  const unsigned short* Wt0 = Wt;
  const unsigned short* Wt1 = Wt + 24576;
  const unsigned short* Wt2 = Wt + 40960;
  const int ntiles = (M + 63) >> 6;
  const int cg2 = wave & 3, rg = wave >> 2;

  // ---- stage bias/LN params into LDS ----
  for (int i = tid; i < 448; i += 512) {
    float v;
    if (i < 128) v = a.b0[set][i];
    else if (i < 256) v = a.b1[set][i - 128];
    else if (i < 320) v = a.b2[set][i - 256];
    else if (i < 384) v = a.gm[set][i - 320];
    else v = a.bt[set][i - 384];
    ((float*)(sm + OFF_PAR))[i] = v;
  }
  const float* PAR = (const float*)(sm + OFF_PAR);

  // ---- persistent weight fragments, deduped across waves ----
  bf16x8 w0f[6], w1f[4], w2f[4];
#pragma unroll
  for (int kk = 0; kk < 6; ++kk)
    w0f[kk] = *(const bf16x8*)(Wt0 + (wave * 16 + lrow) * 192 + kk * 32 + cg * 8);
#pragma unroll
  for (int kk = 0; kk < 4; ++kk)
    w1f[kk] = *(const bf16x8*)(Wt1 + (wave * 16 + lrow) * 128 + kk * 32 + cg * 8);
#pragma unroll
  for (int kk = 0; kk < 4; ++kk)
    w2f[kk] = *(const bf16x8*)(Wt2 + (cg2 * 16 + lrow) * 128 + kk * 32 + cg * 8);

  // staging map: row = (tid>>5)*4 + ((tid&31)>>3), float-octet oct = tid&7
  const int srow = (tid >> 5) * 4 + ((tid & 31) >> 3), oct = tid & 7;

  int4 pxd, pxs, pat;
  auto LOADT = [&](int tt) {
    const int row = tt * 64 + srow;
    if (EDGE) {
      const int d = dstI[row], s2 = srcI[row];
      pxd = *(const int4*)(xb + (size_t)d * 64 + oct * 8);
      pxs = *(const int4*)(xb + (size_t)s2 * 64 + oct * 8);
      pat = ldpk(attrf + (size_t)row * 64 + oct * 8);
    } else {
      const int rr = min(row, M - 1);
      pxd = ldpk(g1 + (size_t)rr * 64 + oct * 8);
      pxs = ldpk(g2 + (size_t)rr * 64 + oct * 8);
      pat = *(const int4*)(xb + (size_t)rr * 64 + oct * 8);
    }
  };
  auto STAGE = [&]() {
    char* a0 = sm + OFF_A + srow * 384;
    const int swz = (srow & 7) << 4;
    *(int4*)(a0 + ((oct * 16) ^ swz)) = pxd;
    *(int4*)(a0 + ((128 + oct * 16) ^ swz)) = pxs;
    *(int4*)(a0 + ((256 + oct * 16) ^ swz)) = pat;
  };

  int t = bid0;
  if (t >= ntiles) return;
  LOADT(t);
  STAGE();

  for (; t < ntiles; t += NBLK) {
    const int tn = t + NBLK;
    const bool more = tn < ntiles;
    __syncthreads();  // (a) A(t) + PAR visible
    if (more) LOADT(tn);  // next-tile global loads ride under the MFMA phases
    // ---------------- L0: A[192] -> H0[128], relu ----------------
    {
      const f32x4 bb0 = *(const f32x4*)(PAR + wave * 16 + cg * 4);
#pragma unroll
      for (int rt = 0; rt < 4; ++rt) {
        const int row = rt * 16 + lrow, swz = (row & 7) << 4;
        const char* ab = sm + OFF_A + row * 384;
        f32x4 acc = {0.f, 0.f, 0.f, 0.f};
#pragma unroll
        for (int kk = 0; kk < 6; ++kk)
          acc = MFMA(w0f[kk], *(const bf16x8*)(ab + ((kk * 64 + cg * 16) ^ swz)), acc);
        f32x4 h;
#pragma unroll
        for (int q = 0; q < 4; ++q) h[q] = fmaxf(acc[q] + bb0[q], 0.f);
        *(unsigned long long*)(sm + OFF_H0 + row * 256 + ((wave * 32 + cg * 8) ^ swz)) = pk4(h);
      }
    }
    __syncthreads();  // (c) H0 ready
    // ---------------- L1: H0 -> H1 (A[0,256) overlay), relu ----------------
    {
      const f32x4 bb1 = *(const f32x4*)(PAR + 128 + wave * 16 + cg * 4);
#pragma unroll
      for (int rt = 0; rt < 4; ++rt) {
        const int row = rt * 16 + lrow, swz = (row & 7) << 4;
        const char* hb = sm + OFF_H0 + row * 256;
        f32x4 acc = {0.f, 0.f, 0.f, 0.f};
#pragma unroll
        for (int kk = 0; kk < 4; ++kk)
          acc = MFMA(w1f[kk], *(const bf16x8*)(hb + ((kk * 64 + cg * 16) ^ swz)), acc);
        f32x4 h;
#pragma unroll
        for (int q = 0; q < 4; ++q) h[q] = fmaxf(acc[q] + bb1[q], 0.f);
        *(unsigned long long*)(sm + OFF_A + row * 384 + ((wave * 32 + cg * 8) ^ swz)) = pk4(h);
      }
    }
    __syncthreads();  // (d) H1 ready
    // ---------------- L2p: H1 -> acc + bias, LN partials ----------------
    f32x4 accE[2];
    {
      const f32x4 bb2 = *(const f32x4*)(PAR + 256 + cg2 * 16 + cg * 4);
#pragma unroll
      for (int j = 0; j < 2; ++j) {
        const int row = (rg * 2 + j) * 16 + lrow, swz = (row & 7) << 4;
        const char* hb = sm + OFF_A + row * 384;
        f32x4 acc = {0.f, 0.f, 0.f, 0.f};
#pragma unroll
        for (int kk = 0; kk < 4; ++kk)
          acc = MFMA(w2f[kk], *(const bf16x8*)(hb + ((kk * 64 + cg * 16) ^ swz)), acc);
#pragma unroll
        for (int q = 0; q < 4; ++q) acc[q] += bb2[q];
        float s = acc[0] + acc[1] + acc[2] + acc[3];
        float ss = acc[0] * acc[0] + acc[1] * acc[1] + acc[2] * acc[2] + acc[3] * acc[3];
        s += __shfl_xor(s, 16, 64); s += __shfl_xor(s, 32, 64);
        ss += __shfl_xor(ss, 16, 64); ss += __shfl_xor(ss, 32, 64);
        if (cg == 0) *(float2*)(sm + OFF_P + row * 32 + cg2 * 8) = make_float2(s, ss);
        accE[j] = acc;
      }
    }
    __syncthreads();  // (e) partials ready; A free for next stage
    // ---------------- epilogue: LN + residual(global, L2-hit) + store ----------------
    {
      const f32x4 gv = *(const f32x4*)(PAR + 320 + cg2 * 16 + cg * 4);
      const f32x4 bv = *(const f32x4*)(PAR + 384 + cg2 * 16 + cg * 4);
#pragma unroll
      for (int j = 0; j < 2; ++j) {
        const int row = (rg * 2 + j) * 16 + lrow, gr = t * 64 + row;
        float4 p0 = *(const float4*)(sm + OFF_P + row * 32);
        float4 p1 = *(const float4*)(sm + OFF_P + row * 32 + 16);
        float s = p0.x + p0.z + p1.x + p1.z, ss = p0.y + p0.w + p1.y + p1.w;
        float mean = s * (1.f / 64.f);
        float var = fmaxf(ss * (1.f / 64.f) - mean * mean, 0.f);
        float inv = rsqrtf(var + 1e-5f);
        const int col = cg2 * 16 + cg * 4;
        const int grc = EDGE ? gr : min(gr, M - 1);
        const f32x4 r = *(const f32x4*)(attrf + (size_t)grc * 64 + col);
        f32x4 av = accE[j], o;
#pragma unroll
        for (int q = 0; q < 4; ++q) o[q] = (av[q] - mean) * inv * gv[q] + bv[q] + r[q];
        if (EDGE || gr < M) *(f32x4*)(outp + (size_t)gr * 64 + col) = o;
      }
    }
    if (more) STAGE();
  }
}

// ---- K_agg: CSR segment-sum, both sets, one wave/node, perm lookahead ----
__global__ __launch_bounds__(256) void agg_k(const float* __restrict__ em,
                                             const float* __restrict__ ew,
                                             const int* __restrict__ permM,
                                             const int* __restrict__ permW,
                                             const int* __restrict__ rpM,
                                             const int* __restrict__ rpW,
                                             float* __restrict__ aggm,
                                             float* __restrict__ aggw) {
  const int lane = threadIdx.x & 63;
  const int r4 = lane >> 4, cq = lane & 15;
  const int w = (blockIdx.x * 256 + threadIdx.x) >> 6;
  const int nw = gridDim.x * 4;
  for (int dd = w; dd < 2 * NNODES; dd += nw) {
    const bool s1 = dd >= NNODES;
    const int d = s1 ? dd - NNODES : dd;
    const float* oute = s1 ? ew : em;
    const int* perm = s1 ? permW : permM;
    const int* rp = s1 ? rpW : rpM;
    const int s = rp[d], e = rp[d + 1];
    f32x4 acc = {0.f, 0.f, 0.f, 0.f};
    int j = s + r4;
    int row0 = (j < e) ? perm[j] : -1;
    while (row0 >= 0) {
      const int j1 = j + 4;
      const int row1 = (j1 < e) ? perm[j1] : -1;  // lookahead overlaps row load
      const f32x4 v = *(const f32x4*)(oute + (size_t)row0 * 64 + cq * 4);
#pragma unroll
      for (int q = 0; q < 4; ++q) acc[q] += v[q];
      row0 = row1; j = j1;
    }
#pragma unroll
    for (int q = 0; q < 4; ++q) {
      acc[q] += __shfl_xor(acc[q], 16, 64);
      acc[q] += __shfl_xor(acc[q], 32, 64);
    }
    float* agg = s1 ? aggw : aggm;
    if (r4 == 0) *(f32x4*)(agg + (size_t)d * 64 + cq * 4) = acc;
  }
}

// ---- prep: weights -> bf16 [out][in] (upd-W0 rotated); x -> bf16 table ----
struct PrepArgs { const float* w[9]; unsigned short* wt[3]; };

__global__ void prep_w(PrepArgs pa) {
  int i = blockIdx.x * 256 + threadIdx.x;
  if (i >= 3 * 49152) return;
  int mlp = i / 49152;
  int rem = i - mlp * 49152;
  int mat, off, K, N;
  if (rem < 24576)      { mat = 0; off = 0;     K = 192; N = 128; }
  else if (rem < 40960) { mat = 1; off = 24576; K = 128; N = 128; }
  else                  { mat = 2; off = 40960; K = 128; N = 64;  }
  int local = rem - off;
  int n = local / K, k = local - n * K;
  if (mlp == 2 && mat == 0) k = (k + 64) % 192;  // node concat [aggm|aggw|x]
  pa.wt[mlp][rem] = f2bf(pa.w[mlp * 3 + mat][k * N + n]);
}

__global__ void prep_x(const float* __restrict__ x, unsigned short* __restrict__ xb) {
  int i = blockIdx.x * 256 + threadIdx.x;
  if (i < NNODES * 8) *(int4*)(xb + (size_t)i * 8) = ldpk(x + (size_t)i * 8);
}

__global__ void zero_f4(float4* p, int n) {
  int i = blockIdx.x * blockDim.x + threadIdx.x;
  if (i < n) p[i] = make_float4(0.f, 0.f, 0.f, 0.f);
}

// ---- counting sort by dst: hist -> scan(rowptr) -> scatter(perm) ----
__global__ void hist_k(const int* __restrict__ dM, const int* __restrict__ dW,
                       int* __restrict__ curM, int* __restrict__ curW, int E) {
  int i = blockIdx.x * 256 + threadIdx.x;
  if (i < E) {
    atomicAdd(curM + dM[i], 1);
    atomicAdd(curW + dW[i], 1);
  }
}

__global__ __launch_bounds__(1024) void scan_k(int* __restrict__ curM, int* __restrict__ curW,
                                               int* __restrict__ rpM, int* __restrict__ rpW) {
  __shared__ int buf[1024];
  int* cur = blockIdx.x ? curW : curM;
  int* rp = blockIdx.x ? rpW : rpM;
  const int tid = threadIdx.x, base = tid * 49;
  const int lim = min(base + 49, NNODES);
  int p = 0;
  for (int b = base; b < lim; ++b) p += cur[b];
  buf[tid] = p;
  __syncthreads();
  const int own = p;
  for (int off = 1; off < 1024; off <<= 1) {
    int nv = (tid >= off) ? buf[tid - off] : 0;
    __syncthreads();
    buf[tid] += nv;
    __syncthreads();
  }
  int running = buf[tid] - own;  // exclusive prefix
  for (int b = base; b < lim; ++b) {
    int h = cur[b];
    cur[b] = running;
    rp[b] = running;
    running += h;
  }
  if (tid == 1023) rp[NNODES] = buf[1023];
}

__global__ void scatter_k(const int* __restrict__ dM, const int* __restrict__ dW,
                          int* __restrict__ curM, int* __restrict__ curW,
                          int* __restrict__ permM, int* __restrict__ permW, int E) {
  int i = blockIdx.x * 256 + threadIdx.x;
  if (i < E) {
    int p = atomicAdd(curM + dM[i], 1);
    permM[p] = i;
    p = atomicAdd(curW + dW[i], 1);
    permW[p] = i;
  }
}

extern "C" void kernel_launch(void* const* d_in, const int* in_sizes, int n_in,
                              void* d_out, int out_size, void* d_ws, size_t ws_size,
                              hipStream_t stream) {
  const float* x      = (const float*)d_in[0];
  const int*   meIdx  = (const int*)d_in[1];
  const float* meAttr = (const float*)d_in[2];
  const int*   weIdx  = (const int*)d_in[3];
  const float* weAttr = (const float*)d_in[4];

  float* out_x  = (float*)d_out;
  float* out_em = out_x + (size_t)NNODES * 64;
  float* out_ew = out_em + (size_t)NEDGES * 64;

  char* ws = (char*)d_ws;
  unsigned short* WtM = (unsigned short*)ws;                    // 3 x 98304
  unsigned short* WtW = (unsigned short*)(ws + 98304);
  unsigned short* WtU = (unsigned short*)(ws + 196608);
  unsigned short* xb  = (unsigned short*)(ws + 294912);         // 6.4 MB
  float* aggm = (float*)(ws + 6694912);                         // 12.8 MB
  float* aggw = (float*)(ws + 19494912);                        // 12.8 MB
  char* p = ws + 32294912;
  int* curM  = (int*)p;                                         // 200 KB
  int* curW  = curM + NNODES;                                   // 200 KB
  int* rpM   = (int*)(p + 400000);                              // 50016 ints
  int* rpW   = rpM + 50016;
  int* permM = rpW + 50016;                                     // 3.2 MB
  int* permW = permM + NEDGES;                                  // end ~39.5 MB

  zero_f4<<<dim3(98), dim3(256), 0, stream>>>((float4*)curM, 25000);

  PrepArgs pa;
  for (int m = 0; m < 3; ++m)
    for (int l = 0; l < 3; ++l)
      pa.w[m * 3 + l] = (const float*)d_in[5 + m * 8 + l * 2];
  pa.wt[0] = WtM; pa.wt[1] = WtW; pa.wt[2] = WtU;
  prep_w<<<dim3(576), dim3(256), 0, stream>>>(pa);
  prep_x<<<dim3(1563), dim3(256), 0, stream>>>(x, xb);

  hist_k<<<dim3(3125), dim3(256), 0, stream>>>(meIdx + NEDGES, weIdx + NEDGES, curM, curW, NEDGES);
  scan_k<<<dim3(2), dim3(1024), 0, stream>>>(curM, curW, rpM, rpW);
  scatter_k<<<dim3(3125), dim3(256), 0, stream>>>(meIdx + NEDGES, weIdx + NEDGES,
                                                  curM, curW, permM, permW, NEDGES);

  // merged edge MLP (set0 = mesh, set1 = world); x_i = x[dst], x_j = x[src]
  MArgs ea = {};
  ea.xb = xb;
  ea.attrf[0] = meAttr;          ea.attrf[1] = weAttr;
  ea.src[0] = meIdx;             ea.src[1] = weIdx;
  ea.dst[0] = meIdx + NEDGES;    ea.dst[1] = weIdx + NEDGES;
  ea.Wt[0] = WtM;                ea.Wt[1] = WtW;
  ea.b0[0] = (const float*)d_in[6];   ea.b0[1] = (const float*)d_in[14];
  ea.b1[0] = (const float*)d_in[8];   ea.b1[1] = (const float*)d_in[16];
  ea.b2[0] = (const float*)d_in[10];  ea.b2[1] = (const float*)d_in[18];
  ea.gm[0] = (const float*)d_in[11];  ea.gm[1] = (const float*)d_in[19];
  ea.bt[0] = (const float*)d_in[12];  ea.bt[1] = (const float*)d_in[20];
  ea.outp[0] = out_em;           ea.outp[1] = out_ew;
  mlp_block<true><<<dim3(2 * NBLK), dim3(512), 0, stream>>>(ea, NEDGES);

  // merged CSR segment sums
  agg_k<<<dim3(2048), dim3(256), 0, stream>>>(out_em, out_ew, permM, permW, rpM, rpW, aggm, aggw);

  // node update: A = [aggm | aggw | x], residual = x
  MArgs na = {};
  na.xb = xb;
  na.g1[0] = aggm; na.g2[0] = aggw;
  na.attrf[0] = x;
  na.Wt[0] = WtU;
  na.b0[0] = (const float*)d_in[22];
  na.b1[0] = (const float*)d_in[24];
  na.b2[0] = (const float*)d_in[26];
  na.gm[0] = (const float*)d_in[27];
  na.bt[0] = (const float*)d_in[28];
  na.outp[0] = out_x;
  mlp_block<false><<<dim3(NBLK), dim3(512), 0, stream>>>(na, NNODES);
}

// Round 10
// 750.297 us; speedup vs baseline: 1.6930x; 1.2300x over previous
//
#include <hip/hip_runtime.h>

// InteractionNetwork — decomposed:
//   prep_x : x -> bf16 table xb (6.4 MB): edge gathers read 128B rows.
//   K_mlp  : edge (two dispatches, plain args — avoids the R9 struct spill)
//            / node MLP+LN, no atomics, direct coalesced stores.
//   K_agg  : CSR segment-sum, both sets, 8 rows in flight, perm lookahead.
//   sort   : hist -> parallel chunk-scan -> scatter(perm).
// MLP: OUT^T = W^T * X^T, weight frags persistent+deduped in regs, activations
// through XOR-swizzled LDS, 4 barriers/tile, residual re-read from global (L2).

#define NNODES 50000
#define NEDGES 800000
#define NBLK 512
#define NCHUNK 196  // ceil(50000/256) chunks per set

typedef __bf16 bf16x8 __attribute__((ext_vector_type(8)));
typedef float f32x4 __attribute__((ext_vector_type(4)));
#define MFMA(a, b, c) __builtin_amdgcn_mfma_f32_16x16x32_bf16(a, b, c, 0, 0, 0)

// LDS map (bytes)
#define OFF_A 0       // [64][192] bf16 stride 384, swizzled; [0,256) reused as H1
#define OFF_H0 24576  // [64][128] bf16 stride 256, swizzled
#define OFF_P 40960   // [64 rows][4 float2] (s,ss) partials
#define OFF_PAR 43008 // b0[128] b1[128] b2[64] gam[64] bet[64] = 448 f32
#define SMEM 44800

__device__ __forceinline__ unsigned short f2bf(float f) {
  unsigned u = __builtin_bit_cast(unsigned, f);
  u = (u + 0x7fffu + ((u >> 16) & 1u)) >> 16;
  return (unsigned short)u;
}
__device__ __forceinline__ unsigned long long pk4(f32x4 v) {
  union { unsigned short h[4]; unsigned long long u; } p;
  p.h[0] = f2bf(v[0]); p.h[1] = f2bf(v[1]); p.h[2] = f2bf(v[2]); p.h[3] = f2bf(v[3]);
  return p.u;
}
__device__ __forceinline__ int4 pk8(float4 a, float4 b) {
  union { unsigned short us[8]; int4 v; } u;
  u.us[0] = f2bf(a.x); u.us[1] = f2bf(a.y); u.us[2] = f2bf(a.z); u.us[3] = f2bf(a.w);
  u.us[4] = f2bf(b.x); u.us[5] = f2bf(b.y); u.us[6] = f2bf(b.z); u.us[7] = f2bf(b.w);
  return u.v;
}
__device__ __forceinline__ int4 ldpk(const float* p) {
  return pk8(*(const float4*)p, *(const float4*)(p + 4));
}

// EDGE: A = [xb[dst] | xb[src] | attr(g3)], residual = attr. Plain args.
// NODE: A = [aggm(g1) | aggw(g2) | x(g3)],  residual = x. (W0 pre-rotated.)
template <bool EDGE>
__global__ __launch_bounds__(512, 4) void mlp_block(
    const float* __restrict__ g1, const float* __restrict__ g2,
    const float* __restrict__ g3, const unsigned short* __restrict__ xb,
    const int* __restrict__ srcI, const int* __restrict__ dstI,
    const unsigned short* __restrict__ Wt,
    const float* __restrict__ b0, const float* __restrict__ b1,
    const float* __restrict__ b2, const float* __restrict__ gam,
    const float* __restrict__ bet, float* __restrict__ outp, int M) {
  __shared__ __align__(16) char sm[SMEM];
  const int tid = threadIdx.x, lane = tid & 63, wave = tid >> 6;
  const int lrow = lane & 15, cg = lane >> 4;
  const unsigned short* Wt0 = Wt;
  const unsigned short* Wt1 = Wt + 24576;
  const unsigned short* Wt2 = Wt + 40960;
  const int ntiles = (M + 63) >> 6;
  const int cg2 = wave & 3, rg = wave >> 2;

  // ---- stage bias/LN params into LDS ----
  for (int i = tid; i < 448; i += 512) {
    float v;
    if (i < 128) v = b0[i];
    else if (i < 256) v = b1[i - 128];
    else if (i < 320) v = b2[i - 256];
    else if (i < 384) v = gam[i - 320];
    else v = bet[i - 384];
    ((float*)(sm + OFF_PAR))[i] = v;
  }
  const float* PAR = (const float*)(sm + OFF_PAR);

  // ---- persistent weight fragments, deduped across waves ----
  bf16x8 w0f[6], w1f[4], w2f[4];
#pragma unroll
  for (int kk = 0; kk < 6; ++kk)
    w0f[kk] = *(const bf16x8*)(Wt0 + (wave * 16 + lrow) * 192 + kk * 32 + cg * 8);
#pragma unroll
  for (int kk = 0; kk < 4; ++kk)
    w1f[kk] = *(const bf16x8*)(Wt1 + (wave * 16 + lrow) * 128 + kk * 32 + cg * 8);
#pragma unroll
  for (int kk = 0; kk < 4; ++kk)
    w2f[kk] = *(const bf16x8*)(Wt2 + (cg2 * 16 + lrow) * 128 + kk * 32 + cg * 8);

  // staging map: row = (tid>>5)*4 + ((tid&31)>>3), float-octet oct = tid&7
  const int srow = (tid >> 5) * 4 + ((tid & 31) >> 3), oct = tid & 7;

  int4 pxd, pxs, pat;
  auto LOADT = [&](int tt) {
    const int row = tt * 64 + srow;
    if (EDGE) {
      const int d = dstI[row], s2 = srcI[row];
      pxd = *(const int4*)(xb + (size_t)d * 64 + oct * 8);
      pxs = *(const int4*)(xb + (size_t)s2 * 64 + oct * 8);
      pat = ldpk(g3 + (size_t)row * 64 + oct * 8);
    } else {
      const int rr = min(row, M - 1);
      pxd = ldpk(g1 + (size_t)rr * 64 + oct * 8);
      pxs = ldpk(g2 + (size_t)rr * 64 + oct * 8);
      pat = ldpk(g3 + (size_t)rr * 64 + oct * 8);
    }
  };
  auto STAGE = [&]() {
    char* a0 = sm + OFF_A + srow * 384;
    const int swz = (srow & 7) << 4;
    *(int4*)(a0 + ((oct * 16) ^ swz)) = pxd;
    *(int4*)(a0 + ((128 + oct * 16) ^ swz)) = pxs;
    *(int4*)(a0 + ((256 + oct * 16) ^ swz)) = pat;
  };

  int t = blockIdx.x;
  if (t >= ntiles) return;
  LOADT(t);
  STAGE();

  for (; t < ntiles; t += NBLK) {
    const int tn = t + NBLK;
    const bool more = tn < ntiles;
    __syncthreads();  // (a) A(t) + PAR visible
    if (more) LOADT(tn);  // next-tile global loads ride under the MFMA phases
    // ---------------- L0: A[192] -> H0[128], relu ----------------
    {
      const f32x4 bb0 = *(const f32x4*)(PAR + wave * 16 + cg * 4);
#pragma unroll
      for (int rt = 0; rt < 4; ++rt) {
        const int row = rt * 16 + lrow, swz = (row & 7) << 4;
        const char* ab = sm + OFF_A + row * 384;
        f32x4 acc = {0.f, 0.f, 0.f, 0.f};
#pragma unroll
        for (int kk = 0; kk < 6; ++kk)
          acc = MFMA(w0f[kk], *(const bf16x8*)(ab + ((kk * 64 + cg * 16) ^ swz)), acc);
        f32x4 h;
#pragma unroll
        for (int q = 0; q < 4; ++q) h[q] = fmaxf(acc[q] + bb0[q], 0.f);
        *(unsigned long long*)(sm + OFF_H0 + row * 256 + ((wave * 32 + cg * 8) ^ swz)) = pk4(h);
      }
    }
    __syncthreads();  // (c) H0 ready
    // ---------------- L1: H0 -> H1 (A[0,256) overlay), relu ----------------
    {
      const f32x4 bb1 = *(const f32x4*)(PAR + 128 + wave * 16 + cg * 4);
#pragma unroll
      for (int rt = 0; rt < 4; ++rt) {
        const int row = rt * 16 + lrow, swz = (row & 7) << 4;
        const char* hb = sm + OFF_H0 + row * 256;
        f32x4 acc = {0.f, 0.f, 0.f, 0.f};
#pragma unroll
        for (int kk = 0; kk < 4; ++kk)
          acc = MFMA(w1f[kk], *(const bf16x8*)(hb + ((kk * 64 + cg * 16) ^ swz)), acc);
        f32x4 h;
#pragma unroll
        for (int q = 0; q < 4; ++q) h[q] = fmaxf(acc[q] + bb1[q], 0.f);
        *(unsigned long long*)(sm + OFF_A + row * 384 + ((wave * 32 + cg * 8) ^ swz)) = pk4(h);
      }
    }
    __syncthreads();  // (d) H1 ready
    // ---------------- L2p: H1 -> acc + bias, LN partials ----------------
    f32x4 accE[2];
    {
      const f32x4 bb2 = *(const f32x4*)(PAR + 256 + cg2 * 16 + cg * 4);
#pragma unroll
      for (int j = 0; j < 2; ++j) {
        const int row = (rg * 2 + j) * 16 + lrow, swz = (row & 7) << 4;
        const char* hb = sm + OFF_A + row * 384;
        f32x4 acc = {0.f, 0.f, 0.f, 0.f};
#pragma unroll
        for (int kk = 0; kk < 4; ++kk)
          acc = MFMA(w2f[kk], *(const bf16x8*)(hb + ((kk * 64 + cg * 16) ^ swz)), acc);
#pragma unroll
        for (int q = 0; q < 4; ++q) acc[q] += bb2[q];
        float s = acc[0] + acc[1] + acc[2] + acc[3];
        float ss = acc[0] * acc[0] + acc[1] * acc[1] + acc[2] * acc[2] + acc[3] * acc[3];
        s += __shfl_xor(s, 16, 64); s += __shfl_xor(s, 32, 64);
        ss += __shfl_xor(ss, 16, 64); ss += __shfl_xor(ss, 32, 64);
        if (cg == 0) *(float2*)(sm + OFF_P + row * 32 + cg2 * 8) = make_float2(s, ss);
        accE[j] = acc;
      }
    }
    __syncthreads();  // (e) partials ready; A free for next stage
    // ---------------- epilogue: LN + residual(global, L2) + store ----------------
    {
      const f32x4 gv = *(const f32x4*)(PAR + 320 + cg2 * 16 + cg * 4);
      const f32x4 bv = *(const f32x4*)(PAR + 384 + cg2 * 16 + cg * 4);
#pragma unroll
      for (int j = 0; j < 2; ++j) {
        const int row = (rg * 2 + j) * 16 + lrow, gr = t * 64 + row;
        float4 p0 = *(const float4*)(sm + OFF_P + row * 32);
        float4 p1 = *(const float4*)(sm + OFF_P + row * 32 + 16);
        float s = p0.x + p0.z + p1.x + p1.z, ss = p0.y + p0.w + p1.y + p1.w;
        float mean = s * (1.f / 64.f);
        float var = fmaxf(ss * (1.f / 64.f) - mean * mean, 0.f);
        float inv = rsqrtf(var + 1e-5f);
        const int col = cg2 * 16 + cg * 4;
        const int grc = EDGE ? gr : min(gr, M - 1);
        const f32x4 r = *(const f32x4*)(g3 + (size_t)grc * 64 + col);
        f32x4 av = accE[j], o;
#pragma unroll
        for (int q = 0; q < 4; ++q) o[q] = (av[q] - mean) * inv * gv[q] + bv[q] + r[q];
        if (EDGE || gr < M) *(f32x4*)(outp + (size_t)gr * 64 + col) = o;
      }
    }
    if (more) STAGE();
  }
}

// ---- K_agg: CSR segment-sum, both sets, 8 rows in flight ----
__global__ __launch_bounds__(256) void agg_k(const float* __restrict__ em,
                                             const float* __restrict__ ew,
                                             const int* __restrict__ permM,
                                             const int* __restrict__ permW,
                                             const int* __restrict__ rpM,
                                             const int* __restrict__ rpW,
                                             float* __restrict__ aggm,
                                             float* __restrict__ aggw) {
  const int lane = threadIdx.x & 63;
  const int r4 = lane >> 4, cq = lane & 15;
  const int w = (blockIdx.x * 256 + threadIdx.x) >> 6;
  const int nw = gridDim.x * 4;
  for (int dd = w; dd < 2 * NNODES; dd += nw) {
    const bool s1 = dd >= NNODES;
    const int d = s1 ? dd - NNODES : dd;
    const float* oute = s1 ? ew : em;
    const int* perm = s1 ? permW : permM;
    const int* rp = s1 ? rpW : rpM;
    const int s = rp[d], e = rp[d + 1];
    f32x4 acc = {0.f, 0.f, 0.f, 0.f}, acc2 = {0.f, 0.f, 0.f, 0.f};
    int j = s + r4;
    for (; j + 4 < e; j += 8) {  // two independent row loads per iter
      const int ra = perm[j], rb = perm[j + 4];
      const f32x4 va = *(const f32x4*)(oute + (size_t)ra * 64 + cq * 4);
      const f32x4 vb = *(const f32x4*)(oute + (size_t)rb * 64 + cq * 4);
#pragma unroll
      for (int q = 0; q < 4; ++q) { acc[q] += va[q]; acc2[q] += vb[q]; }
    }
    if (j < e) {
      const int ra = perm[j];
      const f32x4 va = *(const f32x4*)(oute + (size_t)ra * 64 + cq * 4);
#pragma unroll
      for (int q = 0; q < 4; ++q) acc[q] += va[q];
    }
#pragma unroll
    for (int q = 0; q < 4; ++q) {
      acc[q] += acc2[q];
      acc[q] += __shfl_xor(acc[q], 16, 64);
      acc[q] += __shfl_xor(acc[q], 32, 64);
    }
    float* agg = s1 ? aggw : aggm;
    if (r4 == 0) *(f32x4*)(agg + (size_t)d * 64 + cq * 4) = acc;
  }
}

// ---- prep: weights -> bf16 [out][in] (upd-W0 rotated); x -> bf16 table ----
struct PrepArgs { const float* w[9]; unsigned short* wt[3]; };

__global__ void prep_w(PrepArgs pa) {
  int i = blockIdx.x * 256 + threadIdx.x;
  if (i >= 3 * 49152) return;
  int mlp = i / 49152;
  int rem = i - mlp * 49152;
  int mat, off, K, N;
  if (rem < 24576)      { mat = 0; off = 0;     K = 192; N = 128; }
  else if (rem < 40960) { mat = 1; off = 24576; K = 128; N = 128; }
  else                  { mat = 2; off = 40960; K = 128; N = 64;  }
  int local = rem - off;
  int n = local / K, k = local - n * K;
  if (mlp == 2 && mat == 0) k = (k + 64) % 192;  // node concat [aggm|aggw|x]
  pa.wt[mlp][rem] = f2bf(pa.w[mlp * 3 + mat][k * N + n]);
}

__global__ void prep_x(const float* __restrict__ x, unsigned short* __restrict__ xb) {
  int i = blockIdx.x * 256 + threadIdx.x;
  if (i < NNODES * 8) *(int4*)(xb + (size_t)i * 8) = ldpk(x + (size_t)i * 8);
}

__global__ void zero_f4(float4* p, int n) {
  int i = blockIdx.x * blockDim.x + threadIdx.x;
  if (i < n) p[i] = make_float4(0.f, 0.f, 0.f, 0.f);
}

// ---- counting sort by dst: hist -> parallel chunk scan -> scatter ----
__global__ void hist_k(const int* __restrict__ dM, const int* __restrict__ dW,
                       int* __restrict__ curM, int* __restrict__ curW, int E) {
  int i = blockIdx.x * 256 + threadIdx.x;
  if (i < E) {
    atomicAdd(curM + dM[i], 1);
    atomicAdd(curW + dW[i], 1);
  }
}

// chunk sums: 2*NCHUNK blocks x 64 threads; chunk = 256 counters
__global__ __launch_bounds__(64) void csum_k(const int* __restrict__ curM,
                                             const int* __restrict__ curW,
                                             int* __restrict__ csum) {
  const int c = blockIdx.x, set = c >= NCHUNK, c0 = c - set * NCHUNK;
  const int* cnt = set ? curW : curM;
  const int lane = threadIdx.x;
  const int base = c0 * 256 + lane * 4;
  int s = 0;
  if (base + 3 < NNODES) {
    int4 v = *(const int4*)(cnt + base);
    s = v.x + v.y + v.z + v.w;
  } else {
    for (int k = 0; k < 4; ++k) if (base + k < NNODES) s += cnt[base + k];
  }
#pragma unroll
  for (int off = 1; off < 64; off <<= 1) s += __shfl_xor(s, off, 64);
  if (lane == 0) csum[c] = s;
}

// scan chunk sums (per set) -> exclusive chunk bases
__global__ __launch_bounds__(512) void cscan_k(const int* __restrict__ csum,
                                               int* __restrict__ cbase) {
  __shared__ int buf[512];
  const int tid = threadIdx.x;
  buf[tid] = (tid < 2 * NCHUNK) ? csum[tid] : 0;
  __syncthreads();
  for (int off = 1; off < 512; off <<= 1) {
    int nv = (tid >= off) ? buf[tid - off] : 0;
    __syncthreads();
    buf[tid] += nv;
    __syncthreads();
  }
  if (tid < 2 * NCHUNK) {
    const int set = tid >= NCHUNK;
    int excl = tid ? buf[tid - 1] : 0;
    if (set) excl -= buf[NCHUNK - 1];
    cbase[tid] = excl;
  }
}

// per-chunk exclusive prefix -> rowptr + working copy (overwrites cur)
__global__ __launch_bounds__(64) void rp_k(int* __restrict__ curM, int* __restrict__ curW,
                                           const int* __restrict__ cbase,
                                           int* __restrict__ rpM, int* __restrict__ rpW) {
  const int c = blockIdx.x, set = c >= NCHUNK, c0 = c - set * NCHUNK;
  int* cnt = set ? curW : curM;
  int* rp = set ? rpW : rpM;
  const int lane = threadIdx.x;
  const int idx = c0 * 256 + lane * 4;
  int v[4];
#pragma unroll
  for (int k = 0; k < 4; ++k) v[k] = (idx + k < NNODES) ? cnt[idx + k] : 0;
  const int ls = v[0] + v[1] + v[2] + v[3];
  int ex = ls;
#pragma unroll
  for (int off = 1; off < 64; off <<= 1) {
    int nv = __shfl_up(ex, off, 64);
    if (lane >= off) ex += nv;
  }
  int run = cbase[c] + (ex - ls);  // exclusive base for this lane's 4 slots
#pragma unroll
  for (int k = 0; k < 4; ++k) {
    if (idx + k < NNODES) {
      rp[idx + k] = run;
      cnt[idx + k] = run;
      run += v[k];
    }
  }
  if (c0 == 0 && lane == 0) rp[NNODES] = NEDGES;
}

__global__ void scatter_k(const int* __restrict__ dM, const int* __restrict__ dW,
                          int* __restrict__ curM, int* __restrict__ curW,
                          int* __restrict__ permM, int* __restrict__ permW, int E) {
  int i = blockIdx.x * 256 + threadIdx.x;
  if (i < E) {
    int p = atomicAdd(curM + dM[i], 1);
    permM[p] = i;
    p = atomicAdd(curW + dW[i], 1);
    permW[p] = i;
  }
}

extern "C" void kernel_launch(void* const* d_in, const int* in_sizes, int n_in,
                              void* d_out, int out_size, void* d_ws, size_t ws_size,
                              hipStream_t stream) {
  const float* x      = (const float*)d_in[0];
  const int*   meIdx  = (const int*)d_in[1];
  const float* meAttr = (const float*)d_in[2];
  const int*   weIdx  = (const int*)d_in[3];
  const float* weAttr = (const float*)d_in[4];

  float* out_x  = (float*)d_out;
  float* out_em = out_x + (size_t)NNODES * 64;
  float* out_ew = out_em + (size_t)NEDGES * 64;

  char* ws = (char*)d_ws;
  unsigned short* WtM = (unsigned short*)ws;                    // 3 x 98304
  unsigned short* WtW = (unsigned short*)(ws + 98304);
  unsigned short* WtU = (unsigned short*)(ws + 196608);
  unsigned short* xb  = (unsigned short*)(ws + 294912);         // 6.4 MB
  float* aggm = (float*)(ws + 6694912);                         // 12.8 MB
  float* aggw = (float*)(ws + 19494912);                        // 12.8 MB
  char* p = ws + 32294912;
  int* curM  = (int*)p;                                         // 200 KB
  int* curW  = curM + NNODES;                                   // 200 KB
  int* rpM   = (int*)(p + 400000);                              // 50016 ints
  int* rpW   = rpM + 50016;
  int* permM = rpW + 50016;                                     // 3.2 MB
  int* permW = permM + NEDGES;                                  // 3.2 MB
  int* csum  = permW + NEDGES;                                  // 392 ints
  int* cbase = csum + 512;                                      // end ~39.5 MB

  zero_f4<<<dim3(98), dim3(256), 0, stream>>>((float4*)curM, 25000);

  PrepArgs pa;
  for (int m = 0; m < 3; ++m)
    for (int l = 0; l < 3; ++l)
      pa.w[m * 3 + l] = (const float*)d_in[5 + m * 8 + l * 2];
  pa.wt[0] = WtM; pa.wt[1] = WtW; pa.wt[2] = WtU;
  prep_w<<<dim3(576), dim3(256), 0, stream>>>(pa);
  prep_x<<<dim3(1563), dim3(256), 0, stream>>>(x, xb);

  hist_k<<<dim3(3125), dim3(256), 0, stream>>>(meIdx + NEDGES, weIdx + NEDGES, curM, curW, NEDGES);
  csum_k<<<dim3(2 * NCHUNK), dim3(64), 0, stream>>>(curM, curW, csum);
  cscan_k<<<dim3(1), dim3(512), 0, stream>>>(csum, cbase);
  rp_k<<<dim3(2 * NCHUNK), dim3(64), 0, stream>>>(curM, curW, cbase, rpM, rpW);
  scatter_k<<<dim3(3125), dim3(256), 0, stream>>>(meIdx + NEDGES, weIdx + NEDGES,
                                                  curM, curW, permM, permW, NEDGES);

  // edge MLPs (original order; x_i = x[dst], x_j = x[src])
  mlp_block<true><<<dim3(NBLK), dim3(512), 0, stream>>>(
      nullptr, nullptr, meAttr, xb, meIdx, meIdx + NEDGES, WtM,
      (const float*)d_in[6], (const float*)d_in[8], (const float*)d_in[10],
      (const float*)d_in[11], (const float*)d_in[12],
      out_em, NEDGES);
  mlp_block<true><<<dim3(NBLK), dim3(512), 0, stream>>>(
      nullptr, nullptr, weAttr, xb, weIdx, weIdx + NEDGES, WtW,
      (const float*)d_in[14], (const float*)d_in[16], (const float*)d_in[18],
      (const float*)d_in[19], (const float*)d_in[20],
      out_ew, NEDGES);

  // merged CSR segment sums
  agg_k<<<dim3(4096), dim3(256), 0, stream>>>(out_em, out_ew, permM, permW, rpM, rpW, aggm, aggw);

  // node update: A = [aggm | aggw | x], residual = x
  mlp_block<false><<<dim3(NBLK), dim3(512), 0, stream>>>(
      aggm, aggw, x, nullptr, nullptr, nullptr, WtU,
      (const float*)d_in[22], (const float*)d_in[24], (const float*)d_in[26],
      (const float*)d_in[27], (const float*)d_in[28],
      out_x, NNODES);
}